// Round 1
// baseline (1475.186 us; speedup 1.0000x reference)
//
#include <hip/hip_runtime.h>
#include <math.h>

#define FIN 64
#define HID 64
#define FOUT 40

// ---------------- degree / normalization ----------------

__global__ void count_deg_kernel(const int* __restrict__ dst, unsigned int* __restrict__ deg, int E) {
    int e = blockIdx.x * blockDim.x + threadIdx.x;
    if (e < E) atomicAdd(&deg[dst[e]], 1u);
}

__global__ void dinv_kernel(const unsigned int* __restrict__ deg, float* __restrict__ dinv, int n) {
    int i = blockIdx.x * blockDim.x + threadIdx.x;
    if (i < n) dinv[i] = rsqrtf((float)deg[i] + 1.0f);
}

// ---------------- layer 1 GEMM: h1 = x @ W1 ; agg1 = h1*dinv^2 + b1 ----------------
// 16 nodes per block, 256 threads, each thread computes 4 (node, f) outputs.

__global__ __launch_bounds__(256) void gemm1_kernel(const float* __restrict__ x,
        const float* __restrict__ W, const float* __restrict__ b,
        const float* __restrict__ dinv, float* __restrict__ h,
        float* __restrict__ agg, int n) {
    __shared__ float Wl[64 * 64];
    __shared__ float xs[16 * 64];
    int tid = threadIdx.x;
    #pragma unroll
    for (int i = 0; i < 16; ++i) Wl[tid + 256 * i] = W[tid + 256 * i];
    int nodeBase = blockIdx.x * 16;
    #pragma unroll
    for (int i = 0; i < 4; ++i) {
        int idx = tid + 256 * i;
        int node = nodeBase + (idx >> 6);
        xs[idx] = (node < n) ? x[(size_t)node * 64 + (idx & 63)] : 0.0f;
    }
    __syncthreads();
    int f = tid & 63;
    int nl0 = tid >> 6;  // wave-uniform: 0..3
    float acc[4] = {0.f, 0.f, 0.f, 0.f};
    for (int k = 0; k < 64; ++k) {
        float w = Wl[k * 64 + f];
        #pragma unroll
        for (int i = 0; i < 4; ++i)
            acc[i] += xs[(nl0 + 4 * i) * 64 + k] * w;   // broadcast read per wave
    }
    float bf = b[f];
    #pragma unroll
    for (int i = 0; i < 4; ++i) {
        int node = nodeBase + nl0 + 4 * i;
        if (node < n) {
            float dv = dinv[node];
            h[(size_t)node * 64 + f] = acc[i];
            agg[(size_t)node * 64 + f] = acc[i] * dv * dv + bf;
        }
    }
}

// ---------------- edge scatter layer 1: agg1[dst] += h1[src] * norm ----------------
// 16 lanes per edge, float4 gather, 4 atomicAdds per lane.

__global__ void edge_agg1_kernel(const int* __restrict__ src, const int* __restrict__ dst,
        const float* __restrict__ dinv, const float* __restrict__ h1,
        float* __restrict__ agg1, int E) {
    int t = blockIdx.x * blockDim.x + threadIdx.x;
    int e = t >> 4;
    int l = t & 15;
    if (e >= E) return;
    int s = src[e], d = dst[e];
    float nrm = dinv[s] * dinv[d];
    const float4* hp = (const float4*)(h1 + (size_t)s * 64);
    float4 v = hp[l];
    float* p = agg1 + (size_t)d * 64 + l * 4;
    atomicAdd(p + 0, v.x * nrm);
    atomicAdd(p + 1, v.y * nrm);
    atomicAdd(p + 2, v.z * nrm);
    atomicAdd(p + 3, v.w * nrm);
}

// ---------------- layer 2 GEMM: h2 = relu(agg1) @ W2 ; agg2(d_out) = h2*dinv^2 + b2 ----------------
// 16 nodes per block, 320 threads (5 waves), each thread 2 (node, f) outputs.

__global__ __launch_bounds__(320) void gemm2_kernel(const float* __restrict__ agg1,
        const float* __restrict__ W, const float* __restrict__ b,
        const float* __restrict__ dinv, float* __restrict__ h2,
        float* __restrict__ agg2, int n) {
    __shared__ float Wl[64 * 40];
    __shared__ float xs[16 * 64];
    int tid = threadIdx.x;
    for (int idx = tid; idx < 64 * 40; idx += 320) Wl[idx] = W[idx];
    int nodeBase = blockIdx.x * 16;
    for (int idx = tid; idx < 16 * 64; idx += 320) {
        int node = nodeBase + (idx >> 6);
        float v = (node < n) ? agg1[(size_t)node * 64 + (idx & 63)] : 0.0f;
        xs[idx] = fmaxf(v, 0.0f);   // fused ReLU
    }
    __syncthreads();
    int f = tid % 40;
    int nl0 = tid / 40;  // 0..7
    float acc0 = 0.f, acc1 = 0.f;
    for (int k = 0; k < 64; ++k) {
        float w = Wl[k * 40 + f];
        acc0 += xs[nl0 * 64 + k] * w;
        acc1 += xs[(nl0 + 8) * 64 + k] * w;
    }
    float bf = b[f];
    int node0 = nodeBase + nl0;
    if (node0 < n) {
        float dv = dinv[node0];
        h2[(size_t)node0 * 40 + f] = acc0;
        agg2[(size_t)node0 * 40 + f] = acc0 * dv * dv + bf;
    }
    int node1 = nodeBase + nl0 + 8;
    if (node1 < n) {
        float dv = dinv[node1];
        h2[(size_t)node1 * 40 + f] = acc1;
        agg2[(size_t)node1 * 40 + f] = acc1 * dv * dv + bf;
    }
}

// ---------------- edge scatter layer 2: out[dst] += h2[src] * norm ----------------
// 10 lanes (float4 each) per edge. 40 floats = 160 B, 16 B aligned per row.

__global__ void edge_agg2_kernel(const int* __restrict__ src, const int* __restrict__ dst,
        const float* __restrict__ dinv, const float* __restrict__ h2,
        float* __restrict__ out, int E) {
    int t = blockIdx.x * blockDim.x + threadIdx.x;
    int e = t / 10;
    int q = t % 10;
    if (e >= E) return;
    int s = src[e], d = dst[e];
    float nrm = dinv[s] * dinv[d];
    const float4* hp = (const float4*)(h2 + (size_t)s * 40);
    float4 v = hp[q];
    float* p = out + (size_t)d * 40 + q * 4;
    atomicAdd(p + 0, v.x * nrm);
    atomicAdd(p + 1, v.y * nrm);
    atomicAdd(p + 2, v.z * nrm);
    atomicAdd(p + 3, v.w * nrm);
}

// ---------------- in-place log_softmax over 40 features, one wave per node ----------------

__global__ void logsoftmax_kernel(float* __restrict__ out, int n) {
    int t = blockIdx.x * blockDim.x + threadIdx.x;
    int node = t >> 6;
    int l = t & 63;
    if (node >= n) return;
    float v = (l < 40) ? out[(size_t)node * 40 + l] : -INFINITY;
    float m = v;
    #pragma unroll
    for (int off = 32; off > 0; off >>= 1) m = fmaxf(m, __shfl_xor(m, off));
    float ex = (l < 40) ? expf(v - m) : 0.0f;
    float sum_ = ex;
    #pragma unroll
    for (int off = 32; off > 0; off >>= 1) sum_ += __shfl_xor(sum_, off);
    if (l < 40) out[(size_t)node * 40 + l] = v - m - logf(sum_);
}

extern "C" void kernel_launch(void* const* d_in, const int* in_sizes, int n_in,
                              void* d_out, int out_size, void* d_ws, size_t ws_size,
                              hipStream_t stream) {
    const float* x  = (const float*)d_in[0];
    const int*   ei = (const int*)d_in[1];
    const float* W1 = (const float*)d_in[2];
    const float* b1 = (const float*)d_in[3];
    const float* W2 = (const float*)d_in[4];
    const float* b2 = (const float*)d_in[5];
    float* out = (float*)d_out;

    int N = in_sizes[0] / FIN;     // 100000
    int E = in_sizes[1] / 2;       // 800000
    const int* src = ei;
    const int* dst = ei + E;

    char* ws = (char*)d_ws;
    size_t off = 0;
    auto alloc = [&](size_t bytes) {
        void* p = ws + off;
        off = (off + bytes + 255) & ~(size_t)255;
        return p;
    };
    unsigned int* deg  = (unsigned int*)alloc((size_t)N * 4);
    float*        dinv = (float*)alloc((size_t)N * 4);
    float*        h1   = (float*)alloc((size_t)N * FIN * 4);
    float*        agg1 = (float*)alloc((size_t)N * HID * 4);
    float*        h2   = (float*)alloc((size_t)N * FOUT * 4);

    hipMemsetAsync(deg, 0, (size_t)N * 4, stream);
    count_deg_kernel<<<(E + 255) / 256, 256, 0, stream>>>(dst, deg, E);
    dinv_kernel<<<(N + 255) / 256, 256, 0, stream>>>(deg, dinv, N);
    gemm1_kernel<<<(N + 15) / 16, 256, 0, stream>>>(x, W1, b1, dinv, h1, agg1, N);
    edge_agg1_kernel<<<(E * 16 + 255) / 256, 256, 0, stream>>>(src, dst, dinv, h1, agg1, E);
    gemm2_kernel<<<(N + 15) / 16, 320, 0, stream>>>(agg1, W2, b2, dinv, h2, out, N);
    edge_agg2_kernel<<<(int)(((long long)E * 10 + 255) / 256), 256, 0, stream>>>(src, dst, dinv, h2, out, E);
    logsoftmax_kernel<<<(int)(((long long)N * 64 + 255) / 256), 256, 0, stream>>>(out, N);
}

// Round 2
// 458.046 us; speedup vs baseline: 3.2206x; 3.2206x over previous
//
#include <hip/hip_runtime.h>
#include <math.h>

#define FIN 64
#define HID 64
#define FOUT 40

// ================= degree / normalization =================

__global__ void count_deg_kernel(const int* __restrict__ dst, unsigned int* __restrict__ deg, int E) {
    int e = blockIdx.x * blockDim.x + threadIdx.x;
    if (e < E) atomicAdd(&deg[dst[e]], 1u);
}

__global__ void dinv_kernel(const unsigned int* __restrict__ deg, float* __restrict__ dinv, int n) {
    int i = blockIdx.x * blockDim.x + threadIdx.x;
    if (i < n) dinv[i] = rsqrtf((float)deg[i] + 1.0f);
}

// ================= CSR build: prefix sum over degrees =================
// Each block covers 1024 degree entries.

__global__ __launch_bounds__(256) void blk_reduce_kernel(const unsigned int* __restrict__ deg,
        int* __restrict__ blocksums, int n) {
    int tid = threadIdx.x;
    int base = blockIdx.x * 1024;
    int s = 0;
    #pragma unroll
    for (int j = 0; j < 4; ++j) {
        int i = base + j * 256 + tid;
        if (i < n) s += (int)deg[i];
    }
    #pragma unroll
    for (int off = 1; off < 64; off <<= 1) s += __shfl_xor(s, off);
    __shared__ int wsum[4];
    if ((tid & 63) == 0) wsum[tid >> 6] = s;
    __syncthreads();
    if (tid == 0) blocksums[blockIdx.x] = wsum[0] + wsum[1] + wsum[2] + wsum[3];
}

// Single block: exclusive-scan the (<=1024) block sums; also writes rowstart[n]=E.
__global__ void scan_blocksums_kernel(int* __restrict__ blocksums, int nb,
        int* __restrict__ rowstart, int n) {
    __shared__ int buf[1024];
    int tid = threadIdx.x;
    for (int i = tid; i < nb; i += 256) buf[i] = blocksums[i];
    __syncthreads();
    if (tid == 0) {
        int run = 0;
        for (int i = 0; i < nb; ++i) { int v = buf[i]; buf[i] = run; run += v; }
        rowstart[n] = run;   // == E
    }
    __syncthreads();
    for (int i = tid; i < nb; i += 256) blocksums[i] = buf[i];
}

// Per-block local exclusive scan (+ block offset), writes rowstart and zeroes cursor.
__global__ __launch_bounds__(256) void local_scan_kernel(const unsigned int* __restrict__ deg,
        const int* __restrict__ blockoffs, int* __restrict__ rowstart,
        int* __restrict__ cursor, int n) {
    int tid = threadIdx.x;
    int lane = tid & 63;
    int wid = tid >> 6;
    int base = blockIdx.x * 1024 + tid * 4;
    int v0 = 0, v1 = 0, v2 = 0, v3 = 0;
    if (base + 3 < n) {
        uint4 u = *(const uint4*)(deg + base);
        v0 = u.x; v1 = u.y; v2 = u.z; v3 = u.w;
    } else {
        if (base + 0 < n) v0 = deg[base + 0];
        if (base + 1 < n) v1 = deg[base + 1];
        if (base + 2 < n) v2 = deg[base + 2];
    }
    int tsum = v0 + v1 + v2 + v3;
    int incl = tsum;
    #pragma unroll
    for (int off = 1; off < 64; off <<= 1) {
        int t = __shfl_up(incl, off);
        if (lane >= off) incl += t;
    }
    int excl = incl - tsum;
    __shared__ int wtot[4];
    if (lane == 63) wtot[wid] = incl;
    __syncthreads();
    int woff = 0;
    for (int w = 0; w < wid; ++w) woff += wtot[w];
    int run = blockoffs[blockIdx.x] + woff + excl;
    int r0 = run, r1 = run + v0, r2 = run + v0 + v1, r3 = run + v0 + v1 + v2;
    if (base + 3 < n) {
        *(int4*)(rowstart + base) = make_int4(r0, r1, r2, r3);
        *(int4*)(cursor + base) = make_int4(0, 0, 0, 0);
    } else {
        if (base + 0 < n) { rowstart[base + 0] = r0; cursor[base + 0] = 0; }
        if (base + 1 < n) { rowstart[base + 1] = r1; cursor[base + 1] = 0; }
        if (base + 2 < n) { rowstart[base + 2] = r2; cursor[base + 2] = 0; }
    }
}

// Bucket the src ids by dst.
__global__ void scatter_edges_kernel(const int* __restrict__ src, const int* __restrict__ dst,
        const int* __restrict__ rowstart, int* __restrict__ cursor,
        int* __restrict__ csr_src, int E) {
    int e = blockIdx.x * blockDim.x + threadIdx.x;
    if (e >= E) return;
    int d = dst[e];
    int pos = rowstart[d] + atomicAdd(&cursor[d], 1);
    csr_src[pos] = src[e];
}

// ================= layer 1 GEMM: h1s = (x @ W1) * dinv[node] =================
// 16 nodes per block, 256 threads, each thread computes 4 (node, f) outputs.

__global__ __launch_bounds__(256) void gemm1_kernel(const float* __restrict__ x,
        const float* __restrict__ W, const float* __restrict__ dinv,
        float* __restrict__ h, int n) {
    __shared__ float Wl[64 * 64];
    __shared__ float xs[16 * 64];
    int tid = threadIdx.x;
    #pragma unroll
    for (int i = 0; i < 16; ++i) Wl[tid + 256 * i] = W[tid + 256 * i];
    int nodeBase = blockIdx.x * 16;
    #pragma unroll
    for (int i = 0; i < 4; ++i) {
        int idx = tid + 256 * i;
        int node = nodeBase + (idx >> 6);
        xs[idx] = (node < n) ? x[(size_t)node * 64 + (idx & 63)] : 0.0f;
    }
    __syncthreads();
    int f = tid & 63;
    int nl0 = tid >> 6;  // wave-uniform 0..3
    float acc[4] = {0.f, 0.f, 0.f, 0.f};
    for (int k = 0; k < 64; ++k) {
        float w = Wl[k * 64 + f];
        #pragma unroll
        for (int i = 0; i < 4; ++i)
            acc[i] += xs[(nl0 + 4 * i) * 64 + k] * w;   // broadcast per wave
    }
    #pragma unroll
    for (int i = 0; i < 4; ++i) {
        int node = nodeBase + nl0 + 4 * i;
        if (node < n) h[(size_t)node * 64 + f] = acc[i] * dinv[node];
    }
}

// ================= gather layer 1 =================
// agg1[d] = relu( (h1s[d] + sum_{e->d} h1s[src]) * dinv[d] + b1 )
// One wave per node, lane = feature.

__global__ __launch_bounds__(256) void gather1_kernel(const float* __restrict__ h1s,
        const int* __restrict__ rowstart, const int* __restrict__ csr_src,
        const float* __restrict__ dinv, const float* __restrict__ b,
        float* __restrict__ agg1, int n) {
    int tid = threadIdx.x;
    int node = blockIdx.x * 4 + (tid >> 6);
    int lane = tid & 63;
    if (node >= n) return;
    float acc = h1s[(size_t)node * 64 + lane];   // self-loop (pre-scaled)
    int beg = rowstart[node], end = rowstart[node + 1];
    for (int c = beg; c < end; c += 64) {
        int m = min(64, end - c);
        int myE = (lane < m) ? csr_src[c + lane] : 0;
        for (int j = 0; j < m; ++j) {
            int s = __shfl(myE, j);
            acc += h1s[(size_t)s * 64 + lane];
        }
    }
    float v = acc * dinv[node] + b[lane];
    agg1[(size_t)node * 64 + lane] = fmaxf(v, 0.0f);   // fused ReLU
}

// ================= layer 2 GEMM: h2s = (agg1 @ W2) * dinv[node] =================
// 16 nodes per block, 320 threads (5 waves), each thread 2 (node, f) outputs.

__global__ __launch_bounds__(320) void gemm2_kernel(const float* __restrict__ agg1,
        const float* __restrict__ W, const float* __restrict__ dinv,
        float* __restrict__ h2, int n) {
    __shared__ float Wl[64 * 40];
    __shared__ float xs[16 * 64];
    int tid = threadIdx.x;
    for (int idx = tid; idx < 64 * 40; idx += 320) Wl[idx] = W[idx];
    int nodeBase = blockIdx.x * 16;
    for (int idx = tid; idx < 16 * 64; idx += 320) {
        int node = nodeBase + (idx >> 6);
        xs[idx] = (node < n) ? agg1[(size_t)node * 64 + (idx & 63)] : 0.0f;
    }
    __syncthreads();
    int f = tid % 40;
    int nl0 = tid / 40;  // 0..7
    float acc0 = 0.f, acc1 = 0.f;
    for (int k = 0; k < 64; ++k) {
        float w = Wl[k * 40 + f];
        acc0 += xs[nl0 * 64 + k] * w;
        acc1 += xs[(nl0 + 8) * 64 + k] * w;
    }
    int node0 = nodeBase + nl0;
    if (node0 < n) h2[(size_t)node0 * 40 + f] = acc0 * dinv[node0];
    int node1 = nodeBase + nl0 + 8;
    if (node1 < n) h2[(size_t)node1 * 40 + f] = acc1 * dinv[node1];
}

// ================= gather layer 2 + fused log_softmax =================
// row = (h2s[d] + sum h2s[src]) * dinv[d] + b2 ; out = log_softmax(row)

__global__ __launch_bounds__(256) void gather2_kernel(const float* __restrict__ h2s,
        const int* __restrict__ rowstart, const int* __restrict__ csr_src,
        const float* __restrict__ dinv, const float* __restrict__ b,
        float* __restrict__ out, int n) {
    int tid = threadIdx.x;
    int node = blockIdx.x * 4 + (tid >> 6);
    int lane = tid & 63;
    if (node >= n) return;
    int feat = (lane < 40) ? lane : 0;   // lanes 40..63 shadow feature 0 (no divergence)
    float acc = h2s[(size_t)node * 40 + feat];
    int beg = rowstart[node], end = rowstart[node + 1];
    for (int c = beg; c < end; c += 64) {
        int m = min(64, end - c);
        int myE = (lane < m) ? csr_src[c + lane] : 0;
        for (int j = 0; j < m; ++j) {
            int s = __shfl(myE, j);
            acc += h2s[(size_t)s * 40 + feat];
        }
    }
    float v = (lane < 40) ? acc * dinv[node] + b[lane] : -INFINITY;
    float mx = v;
    #pragma unroll
    for (int off = 32; off; off >>= 1) mx = fmaxf(mx, __shfl_xor(mx, off));
    float ex = (lane < 40) ? expf(v - mx) : 0.0f;
    float sm = ex;
    #pragma unroll
    for (int off = 32; off; off >>= 1) sm += __shfl_xor(sm, off);
    if (lane < 40) out[(size_t)node * 40 + lane] = v - mx - logf(sm);
}

extern "C" void kernel_launch(void* const* d_in, const int* in_sizes, int n_in,
                              void* d_out, int out_size, void* d_ws, size_t ws_size,
                              hipStream_t stream) {
    const float* x  = (const float*)d_in[0];
    const int*   ei = (const int*)d_in[1];
    const float* W1 = (const float*)d_in[2];
    const float* b1 = (const float*)d_in[3];
    const float* W2 = (const float*)d_in[4];
    const float* b2 = (const float*)d_in[5];
    float* out = (float*)d_out;

    int N = in_sizes[0] / FIN;     // 100000
    int E = in_sizes[1] / 2;       // 800000
    const int* src = ei;
    const int* dst = ei + E;

    char* ws = (char*)d_ws;
    size_t off = 0;
    auto alloc = [&](size_t bytes) {
        void* p = ws + off;
        off = (off + bytes + 255) & ~(size_t)255;
        return p;
    };
    int nb = (N + 1023) / 1024;    // 98 scan blocks
    unsigned int* deg       = (unsigned int*)alloc((size_t)N * 4);
    float*        dinv      = (float*)alloc((size_t)N * 4);
    int*          rowstart  = (int*)alloc((size_t)(N + 1) * 4);
    int*          cursor    = (int*)alloc((size_t)N * 4);
    int*          blocksums = (int*)alloc((size_t)nb * 4);
    int*          csr_src   = (int*)alloc((size_t)E * 4);
    float*        h1s       = (float*)alloc((size_t)N * FIN * 4);
    float*        agg1      = (float*)alloc((size_t)N * HID * 4);
    float*        h2s       = (float*)alloc((size_t)N * FOUT * 4);

    hipMemsetAsync(deg, 0, (size_t)N * 4, stream);
    count_deg_kernel<<<(E + 255) / 256, 256, 0, stream>>>(dst, deg, E);
    dinv_kernel<<<(N + 255) / 256, 256, 0, stream>>>(deg, dinv, N);
    blk_reduce_kernel<<<nb, 256, 0, stream>>>(deg, blocksums, N);
    scan_blocksums_kernel<<<1, 256, 0, stream>>>(blocksums, nb, rowstart, N);
    local_scan_kernel<<<nb, 256, 0, stream>>>(deg, blocksums, rowstart, cursor, N);
    scatter_edges_kernel<<<(E + 255) / 256, 256, 0, stream>>>(src, dst, rowstart, cursor, csr_src, E);
    gemm1_kernel<<<(N + 15) / 16, 256, 0, stream>>>(x, W1, dinv, h1s, N);
    gather1_kernel<<<(N + 3) / 4, 256, 0, stream>>>(h1s, rowstart, csr_src, dinv, b1, agg1, N);
    gemm2_kernel<<<(N + 15) / 16, 320, 0, stream>>>(agg1, W2, dinv, h2s, N);
    gather2_kernel<<<(N + 3) / 4, 256, 0, stream>>>(h2s, rowstart, csr_src, dinv, b2, out, N);
}

// Round 3
// 382.733 us; speedup vs baseline: 3.8543x; 1.1968x over previous
//
#include <hip/hip_runtime.h>
#include <math.h>

#define FIN 64
#define HID 64
#define FOUT 40

// ================= degree / normalization =================

__global__ void count_deg_kernel(const int* __restrict__ dst, unsigned int* __restrict__ deg, int E) {
    int e = blockIdx.x * blockDim.x + threadIdx.x;
    if (e < E) atomicAdd(&deg[dst[e]], 1u);
}

__global__ void dinv_kernel(const unsigned int* __restrict__ deg, float* __restrict__ dinv, int n) {
    int i = blockIdx.x * blockDim.x + threadIdx.x;
    if (i < n) dinv[i] = rsqrtf((float)deg[i] + 1.0f);
}

// ================= CSR build: prefix sum over degrees =================

__global__ __launch_bounds__(256) void blk_reduce_kernel(const unsigned int* __restrict__ deg,
        int* __restrict__ blocksums, int n) {
    int tid = threadIdx.x;
    int base = blockIdx.x * 1024;
    int s = 0;
    #pragma unroll
    for (int j = 0; j < 4; ++j) {
        int i = base + j * 256 + tid;
        if (i < n) s += (int)deg[i];
    }
    #pragma unroll
    for (int off = 1; off < 64; off <<= 1) s += __shfl_xor(s, off);
    __shared__ int wsum[4];
    if ((tid & 63) == 0) wsum[tid >> 6] = s;
    __syncthreads();
    if (tid == 0) blocksums[blockIdx.x] = wsum[0] + wsum[1] + wsum[2] + wsum[3];
}

__global__ void scan_blocksums_kernel(int* __restrict__ blocksums, int nb,
        int* __restrict__ rowstart, int n) {
    __shared__ int buf[1024];
    int tid = threadIdx.x;
    for (int i = tid; i < nb; i += 256) buf[i] = blocksums[i];
    __syncthreads();
    if (tid == 0) {
        int run = 0;
        for (int i = 0; i < nb; ++i) { int v = buf[i]; buf[i] = run; run += v; }
        rowstart[n] = run;   // == E
    }
    __syncthreads();
    for (int i = tid; i < nb; i += 256) blocksums[i] = buf[i];
}

__global__ __launch_bounds__(256) void local_scan_kernel(const unsigned int* __restrict__ deg,
        const int* __restrict__ blockoffs, int* __restrict__ rowstart,
        int* __restrict__ cursor, int n) {
    int tid = threadIdx.x;
    int lane = tid & 63;
    int wid = tid >> 6;
    int base = blockIdx.x * 1024 + tid * 4;
    int v0 = 0, v1 = 0, v2 = 0, v3 = 0;
    if (base + 3 < n) {
        uint4 u = *(const uint4*)(deg + base);
        v0 = u.x; v1 = u.y; v2 = u.z; v3 = u.w;
    } else {
        if (base + 0 < n) v0 = deg[base + 0];
        if (base + 1 < n) v1 = deg[base + 1];
        if (base + 2 < n) v2 = deg[base + 2];
    }
    int tsum = v0 + v1 + v2 + v3;
    int incl = tsum;
    #pragma unroll
    for (int off = 1; off < 64; off <<= 1) {
        int t = __shfl_up(incl, off);
        if (lane >= off) incl += t;
    }
    int excl = incl - tsum;
    __shared__ int wtot[4];
    if (lane == 63) wtot[wid] = incl;
    __syncthreads();
    int woff = 0;
    for (int w = 0; w < wid; ++w) woff += wtot[w];
    int run = blockoffs[blockIdx.x] + woff + excl;
    int r0 = run, r1 = run + v0, r2 = run + v0 + v1, r3 = run + v0 + v1 + v2;
    if (base + 3 < n) {
        *(int4*)(rowstart + base) = make_int4(r0, r1, r2, r3);
        *(int4*)(cursor + base) = make_int4(0, 0, 0, 0);
    } else {
        if (base + 0 < n) { rowstart[base + 0] = r0; cursor[base + 0] = 0; }
        if (base + 1 < n) { rowstart[base + 1] = r1; cursor[base + 1] = 0; }
        if (base + 2 < n) { rowstart[base + 2] = r2; cursor[base + 2] = 0; }
    }
}

__global__ void scatter_edges_kernel(const int* __restrict__ src, const int* __restrict__ dst,
        const int* __restrict__ rowstart, int* __restrict__ cursor,
        int* __restrict__ csr_src, int E) {
    int e = blockIdx.x * blockDim.x + threadIdx.x;
    if (e >= E) return;
    int d = dst[e];
    int pos = rowstart[d] + atomicAdd(&cursor[d], 1);
    csr_src[pos] = src[e];
}

// ================= layer 1 GEMM: h1s = (x @ W1) * dinv[node] =================
// No LDS, no barriers. Lane f holds W[:,f] in 64 VGPRs; x rows arrive as
// wave-uniform float4 broadcast loads. 8 nodes per wave-tile, grid-stride.

#define G1_P 8

__global__ __launch_bounds__(256) void gemm1_kernel(const float* __restrict__ x,
        const float* __restrict__ W, const float* __restrict__ dinv,
        float* __restrict__ h, int n) {
    int lane = threadIdx.x & 63;
    int gwave = (blockIdx.x * 256 + threadIdx.x) >> 6;
    int nwaves = gridDim.x * 4;
    float4 Wc[16];
    #pragma unroll
    for (int k4 = 0; k4 < 16; ++k4) {       // each line: coalesced 256 B row read
        Wc[k4].x = W[(k4 * 4 + 0) * 64 + lane];
        Wc[k4].y = W[(k4 * 4 + 1) * 64 + lane];
        Wc[k4].z = W[(k4 * 4 + 2) * 64 + lane];
        Wc[k4].w = W[(k4 * 4 + 3) * 64 + lane];
    }
    int ntiles = (n + G1_P - 1) / G1_P;
    for (int tile = gwave; tile < ntiles; tile += nwaves) {
        int nodeBase = __builtin_amdgcn_readfirstlane(tile * G1_P);
        float acc[G1_P];
        #pragma unroll
        for (int p = 0; p < G1_P; ++p) acc[p] = 0.0f;
        #pragma unroll
        for (int k4 = 0; k4 < 16; ++k4) {
            #pragma unroll
            for (int p = 0; p < G1_P; ++p) {
                int node = nodeBase + p;
                if (node >= n) node = n - 1;          // safe clamp (N%8==0: never taken)
                float4 xb = *(const float4*)(x + (size_t)node * 64 + k4 * 4);
                acc[p] = fmaf(xb.x, Wc[k4].x, acc[p]);
                acc[p] = fmaf(xb.y, Wc[k4].y, acc[p]);
                acc[p] = fmaf(xb.z, Wc[k4].z, acc[p]);
                acc[p] = fmaf(xb.w, Wc[k4].w, acc[p]);
            }
        }
        #pragma unroll
        for (int p = 0; p < G1_P; ++p) {
            int node = nodeBase + p;
            if (node < n) h[(size_t)node * 64 + lane] = acc[p] * dinv[node];
        }
    }
}

// ================= gather layer 1 =================
// agg1[d] = relu( (h1s[d] + sum_{e->d} h1s[src]) * dinv[d] + b1 )

__global__ __launch_bounds__(256) void gather1_kernel(const float* __restrict__ h1s,
        const int* __restrict__ rowstart, const int* __restrict__ csr_src,
        const float* __restrict__ dinv, const float* __restrict__ b,
        float* __restrict__ agg1, int n) {
    int tid = threadIdx.x;
    int node = blockIdx.x * 4 + (tid >> 6);
    int lane = tid & 63;
    if (node >= n) return;
    float acc = h1s[(size_t)node * 64 + lane];   // self-loop (pre-scaled)
    int beg = rowstart[node], end = rowstart[node + 1];
    for (int c = beg; c < end; c += 64) {
        int m = min(64, end - c);
        int myE = (lane < m) ? csr_src[c + lane] : 0;
        for (int j = 0; j < m; ++j) {
            int s = __shfl(myE, j);
            acc += h1s[(size_t)s * 64 + lane];
        }
    }
    float v = acc * dinv[node] + b[lane];
    agg1[(size_t)node * 64 + lane] = fmaxf(v, 0.0f);   // fused ReLU
}

// ================= layer 2 GEMM: h2s = (agg1 @ W2) * dinv[node] =================
// Same register-resident W structure; lanes >=40 shadow column 39, stores masked.

#define G2_P 8

__global__ __launch_bounds__(256) void gemm2_kernel(const float* __restrict__ agg1,
        const float* __restrict__ W, const float* __restrict__ dinv,
        float* __restrict__ h2, int n) {
    int lane = threadIdx.x & 63;
    int col = (lane < 40) ? lane : 39;
    int gwave = (blockIdx.x * 256 + threadIdx.x) >> 6;
    int nwaves = gridDim.x * 4;
    float4 Wc[16];
    #pragma unroll
    for (int k4 = 0; k4 < 16; ++k4) {
        Wc[k4].x = W[(k4 * 4 + 0) * 40 + col];
        Wc[k4].y = W[(k4 * 4 + 1) * 40 + col];
        Wc[k4].z = W[(k4 * 4 + 2) * 40 + col];
        Wc[k4].w = W[(k4 * 4 + 3) * 40 + col];
    }
    int ntiles = (n + G2_P - 1) / G2_P;
    for (int tile = gwave; tile < ntiles; tile += nwaves) {
        int nodeBase = __builtin_amdgcn_readfirstlane(tile * G2_P);
        float acc[G2_P];
        #pragma unroll
        for (int p = 0; p < G2_P; ++p) acc[p] = 0.0f;
        #pragma unroll
        for (int k4 = 0; k4 < 16; ++k4) {
            #pragma unroll
            for (int p = 0; p < G2_P; ++p) {
                int node = nodeBase + p;
                if (node >= n) node = n - 1;
                float4 xb = *(const float4*)(agg1 + (size_t)node * 64 + k4 * 4);
                acc[p] = fmaf(xb.x, Wc[k4].x, acc[p]);
                acc[p] = fmaf(xb.y, Wc[k4].y, acc[p]);
                acc[p] = fmaf(xb.z, Wc[k4].z, acc[p]);
                acc[p] = fmaf(xb.w, Wc[k4].w, acc[p]);
            }
        }
        #pragma unroll
        for (int p = 0; p < G2_P; ++p) {
            int node = nodeBase + p;
            if (node < n && lane < 40) h2[(size_t)node * 40 + lane] = acc[p] * dinv[node];
        }
    }
}

// ================= gather layer 2 + fused log_softmax =================

__global__ __launch_bounds__(256) void gather2_kernel(const float* __restrict__ h2s,
        const int* __restrict__ rowstart, const int* __restrict__ csr_src,
        const float* __restrict__ dinv, const float* __restrict__ b,
        float* __restrict__ out, int n) {
    int tid = threadIdx.x;
    int node = blockIdx.x * 4 + (tid >> 6);
    int lane = tid & 63;
    if (node >= n) return;
    int feat = (lane < 40) ? lane : 0;   // lanes 40..63 shadow feature 0
    float acc = h2s[(size_t)node * 40 + feat];
    int beg = rowstart[node], end = rowstart[node + 1];
    for (int c = beg; c < end; c += 64) {
        int m = min(64, end - c);
        int myE = (lane < m) ? csr_src[c + lane] : 0;
        for (int j = 0; j < m; ++j) {
            int s = __shfl(myE, j);
            acc += h2s[(size_t)s * 40 + feat];
        }
    }
    float v = (lane < 40) ? acc * dinv[node] + b[lane] : -INFINITY;
    float mx = v;
    #pragma unroll
    for (int off = 32; off; off >>= 1) mx = fmaxf(mx, __shfl_xor(mx, off));
    float ex = (lane < 40) ? expf(v - mx) : 0.0f;
    float sm = ex;
    #pragma unroll
    for (int off = 32; off; off >>= 1) sm += __shfl_xor(sm, off);
    if (lane < 40) out[(size_t)node * 40 + lane] = v - mx - logf(sm);
}

extern "C" void kernel_launch(void* const* d_in, const int* in_sizes, int n_in,
                              void* d_out, int out_size, void* d_ws, size_t ws_size,
                              hipStream_t stream) {
    const float* x  = (const float*)d_in[0];
    const int*   ei = (const int*)d_in[1];
    const float* W1 = (const float*)d_in[2];
    const float* b1 = (const float*)d_in[3];
    const float* W2 = (const float*)d_in[4];
    const float* b2 = (const float*)d_in[5];
    float* out = (float*)d_out;

    int N = in_sizes[0] / FIN;     // 100000
    int E = in_sizes[1] / 2;       // 800000
    const int* src = ei;
    const int* dst = ei + E;

    char* ws = (char*)d_ws;
    size_t off = 0;
    auto alloc = [&](size_t bytes) {
        void* p = ws + off;
        off = (off + bytes + 255) & ~(size_t)255;
        return p;
    };
    int nb = (N + 1023) / 1024;    // 98 scan blocks
    unsigned int* deg       = (unsigned int*)alloc((size_t)N * 4);
    float*        dinv      = (float*)alloc((size_t)N * 4);
    int*          rowstart  = (int*)alloc((size_t)(N + 1) * 4);
    int*          cursor    = (int*)alloc((size_t)N * 4);
    int*          blocksums = (int*)alloc((size_t)nb * 4);
    int*          csr_src   = (int*)alloc((size_t)E * 4);
    float*        h1s       = (float*)alloc((size_t)N * FIN * 4);
    float*        agg1      = (float*)alloc((size_t)N * HID * 4);
    float*        h2s       = (float*)alloc((size_t)N * FOUT * 4);

    hipMemsetAsync(deg, 0, (size_t)N * 4, stream);
    count_deg_kernel<<<(E + 255) / 256, 256, 0, stream>>>(dst, deg, E);
    dinv_kernel<<<(N + 255) / 256, 256, 0, stream>>>(deg, dinv, N);
    blk_reduce_kernel<<<nb, 256, 0, stream>>>(deg, blocksums, N);
    scan_blocksums_kernel<<<1, 256, 0, stream>>>(blocksums, nb, rowstart, N);
    local_scan_kernel<<<nb, 256, 0, stream>>>(deg, blocksums, rowstart, cursor, N);
    scatter_edges_kernel<<<(E + 255) / 256, 256, 0, stream>>>(src, dst, rowstart, cursor, csr_src, E);
    gemm1_kernel<<<1024, 256, 0, stream>>>(x, W1, dinv, h1s, N);
    gather1_kernel<<<(N + 3) / 4, 256, 0, stream>>>(h1s, rowstart, csr_src, dinv, b1, agg1, N);
    gemm2_kernel<<<1024, 256, 0, stream>>>(agg1, W2, dinv, h2s, N);
    gather2_kernel<<<(N + 3) / 4, 256, 0, stream>>>(h2s, rowstart, csr_src, dinv, b2, out, N);
}

// Round 4
// 371.428 us; speedup vs baseline: 3.9717x; 1.0304x over previous
//
#include <hip/hip_runtime.h>
#include <hip/hip_bf16.h>
#include <math.h>

#define FIN 64
#define HID 64
#define FOUT 40
#define H2S_STRIDE 64   // bf16 elements; 128 B row stride, one cache line per row

// ================= degree / normalization =================

__global__ void count_deg_kernel(const int* __restrict__ dst, unsigned int* __restrict__ deg, int E) {
    int e = blockIdx.x * blockDim.x + threadIdx.x;
    if (e < E) atomicAdd(&deg[dst[e]], 1u);
}

__global__ void dinv_kernel(const unsigned int* __restrict__ deg, float* __restrict__ dinv, int n) {
    int i = blockIdx.x * blockDim.x + threadIdx.x;
    if (i < n) dinv[i] = rsqrtf((float)deg[i] + 1.0f);
}

// ================= CSR build: prefix sum over degrees =================

__global__ __launch_bounds__(256) void blk_reduce_kernel(const unsigned int* __restrict__ deg,
        int* __restrict__ blocksums, int n) {
    int tid = threadIdx.x;
    int base = blockIdx.x * 1024;
    int s = 0;
    #pragma unroll
    for (int j = 0; j < 4; ++j) {
        int i = base + j * 256 + tid;
        if (i < n) s += (int)deg[i];
    }
    #pragma unroll
    for (int off = 1; off < 64; off <<= 1) s += __shfl_xor(s, off);
    __shared__ int wsum[4];
    if ((tid & 63) == 0) wsum[tid >> 6] = s;
    __syncthreads();
    if (tid == 0) blocksums[blockIdx.x] = wsum[0] + wsum[1] + wsum[2] + wsum[3];
}

__global__ void scan_blocksums_kernel(int* __restrict__ blocksums, int nb,
        int* __restrict__ rowstart, int n) {
    __shared__ int buf[1024];
    int tid = threadIdx.x;
    for (int i = tid; i < nb; i += 256) buf[i] = blocksums[i];
    __syncthreads();
    if (tid == 0) {
        int run = 0;
        for (int i = 0; i < nb; ++i) { int v = buf[i]; buf[i] = run; run += v; }
        rowstart[n] = run;   // == E
    }
    __syncthreads();
    for (int i = tid; i < nb; i += 256) blocksums[i] = buf[i];
}

__global__ __launch_bounds__(256) void local_scan_kernel(const unsigned int* __restrict__ deg,
        const int* __restrict__ blockoffs, int* __restrict__ rowstart,
        int* __restrict__ cursor, int n) {
    int tid = threadIdx.x;
    int lane = tid & 63;
    int wid = tid >> 6;
    int base = blockIdx.x * 1024 + tid * 4;
    int v0 = 0, v1 = 0, v2 = 0, v3 = 0;
    if (base + 3 < n) {
        uint4 u = *(const uint4*)(deg + base);
        v0 = u.x; v1 = u.y; v2 = u.z; v3 = u.w;
    } else {
        if (base + 0 < n) v0 = deg[base + 0];
        if (base + 1 < n) v1 = deg[base + 1];
        if (base + 2 < n) v2 = deg[base + 2];
    }
    int tsum = v0 + v1 + v2 + v3;
    int incl = tsum;
    #pragma unroll
    for (int off = 1; off < 64; off <<= 1) {
        int t = __shfl_up(incl, off);
        if (lane >= off) incl += t;
    }
    int excl = incl - tsum;
    __shared__ int wtot[4];
    if (lane == 63) wtot[wid] = incl;
    __syncthreads();
    int woff = 0;
    for (int w = 0; w < wid; ++w) woff += wtot[w];
    int run = blockoffs[blockIdx.x] + woff + excl;
    int r0 = run, r1 = run + v0, r2 = run + v0 + v1, r3 = run + v0 + v1 + v2;
    if (base + 3 < n) {
        *(int4*)(rowstart + base) = make_int4(r0, r1, r2, r3);
        *(int4*)(cursor + base) = make_int4(0, 0, 0, 0);
    } else {
        if (base + 0 < n) { rowstart[base + 0] = r0; cursor[base + 0] = 0; }
        if (base + 1 < n) { rowstart[base + 1] = r1; cursor[base + 1] = 0; }
        if (base + 2 < n) { rowstart[base + 2] = r2; cursor[base + 2] = 0; }
    }
}

__global__ void scatter_edges_kernel(const int* __restrict__ src, const int* __restrict__ dst,
        const int* __restrict__ rowstart, int* __restrict__ cursor,
        int* __restrict__ csr_src, int E) {
    int e = blockIdx.x * blockDim.x + threadIdx.x;
    if (e >= E) return;
    int d = dst[e];
    int pos = rowstart[d] + atomicAdd(&cursor[d], 1);
    csr_src[pos] = src[e];
}

// ================= layer 1 GEMM: h1s = bf16( (x @ W1) * dinv[node] ) =================
// No LDS, no barriers. Lane f holds W[:,f] in 64 VGPRs; x rows arrive as
// wave-uniform float4 broadcast loads. 8 nodes per wave-tile, grid-stride.

#define G1_P 8

__global__ __launch_bounds__(256) void gemm1_kernel(const float* __restrict__ x,
        const float* __restrict__ W, const float* __restrict__ dinv,
        __hip_bfloat16* __restrict__ h, int n) {
    int lane = threadIdx.x & 63;
    int gwave = (blockIdx.x * 256 + threadIdx.x) >> 6;
    int nwaves = gridDim.x * 4;
    float4 Wc[16];
    #pragma unroll
    for (int k4 = 0; k4 < 16; ++k4) {       // each line: coalesced 256 B row read
        Wc[k4].x = W[(k4 * 4 + 0) * 64 + lane];
        Wc[k4].y = W[(k4 * 4 + 1) * 64 + lane];
        Wc[k4].z = W[(k4 * 4 + 2) * 64 + lane];
        Wc[k4].w = W[(k4 * 4 + 3) * 64 + lane];
    }
    int ntiles = (n + G1_P - 1) / G1_P;
    for (int tile = gwave; tile < ntiles; tile += nwaves) {
        int nodeBase = __builtin_amdgcn_readfirstlane(tile * G1_P);
        float acc[G1_P];
        #pragma unroll
        for (int p = 0; p < G1_P; ++p) acc[p] = 0.0f;
        #pragma unroll
        for (int k4 = 0; k4 < 16; ++k4) {
            #pragma unroll
            for (int p = 0; p < G1_P; ++p) {
                int node = nodeBase + p;
                if (node >= n) node = n - 1;          // safe clamp (N%8==0: never taken)
                float4 xb = *(const float4*)(x + (size_t)node * 64 + k4 * 4);
                acc[p] = fmaf(xb.x, Wc[k4].x, acc[p]);
                acc[p] = fmaf(xb.y, Wc[k4].y, acc[p]);
                acc[p] = fmaf(xb.z, Wc[k4].z, acc[p]);
                acc[p] = fmaf(xb.w, Wc[k4].w, acc[p]);
            }
        }
        #pragma unroll
        for (int p = 0; p < G1_P; ++p) {
            int node = nodeBase + p;
            if (node < n) h[(size_t)node * 64 + lane] = __float2bfloat16(acc[p] * dinv[node]);
        }
    }
}

// ================= gather layer 1 =================
// agg1[d] = relu( (h1s[d] + sum_{e->d} h1s[src]) * dinv[d] + b1 )
// One wave per node, lane = feature. bf16 rows: one 128 B line per gather.

__global__ __launch_bounds__(256) void gather1_kernel(const __hip_bfloat16* __restrict__ h1s,
        const int* __restrict__ rowstart, const int* __restrict__ csr_src,
        const float* __restrict__ dinv, const float* __restrict__ b,
        float* __restrict__ agg1, int n) {
    int tid = threadIdx.x;
    int node = blockIdx.x * 4 + (tid >> 6);
    int lane = tid & 63;
    if (node >= n) return;
    float acc = __bfloat162float(h1s[(size_t)node * 64 + lane]);   // self-loop (pre-scaled)
    int beg = rowstart[node], end = rowstart[node + 1];
    for (int c = beg; c < end; c += 64) {
        int m = min(64, end - c);
        int myE = (lane < m) ? csr_src[c + lane] : 0;
        for (int j = 0; j < m; ++j) {
            int s = __shfl(myE, j);
            acc += __bfloat162float(h1s[(size_t)s * 64 + lane]);
        }
    }
    float v = acc * dinv[node] + b[lane];
    agg1[(size_t)node * 64 + lane] = fmaxf(v, 0.0f);   // fused ReLU
}

// ================= layer 2 GEMM: h2s = bf16( (agg1 @ W2) * dinv[node] ) =================
// Register-resident W; lanes >=40 shadow column 39, stores masked.
// Row stride padded to 64 bf16 (128 B) so each row is one aligned line.

#define G2_P 8

__global__ __launch_bounds__(256) void gemm2_kernel(const float* __restrict__ agg1,
        const float* __restrict__ W, const float* __restrict__ dinv,
        __hip_bfloat16* __restrict__ h2, int n) {
    int lane = threadIdx.x & 63;
    int col = (lane < 40) ? lane : 39;
    int gwave = (blockIdx.x * 256 + threadIdx.x) >> 6;
    int nwaves = gridDim.x * 4;
    float4 Wc[16];
    #pragma unroll
    for (int k4 = 0; k4 < 16; ++k4) {
        Wc[k4].x = W[(k4 * 4 + 0) * 40 + col];
        Wc[k4].y = W[(k4 * 4 + 1) * 40 + col];
        Wc[k4].z = W[(k4 * 4 + 2) * 40 + col];
        Wc[k4].w = W[(k4 * 4 + 3) * 40 + col];
    }
    int ntiles = (n + G2_P - 1) / G2_P;
    for (int tile = gwave; tile < ntiles; tile += nwaves) {
        int nodeBase = __builtin_amdgcn_readfirstlane(tile * G2_P);
        float acc[G2_P];
        #pragma unroll
        for (int p = 0; p < G2_P; ++p) acc[p] = 0.0f;
        #pragma unroll
        for (int k4 = 0; k4 < 16; ++k4) {
            #pragma unroll
            for (int p = 0; p < G2_P; ++p) {
                int node = nodeBase + p;
                if (node >= n) node = n - 1;
                float4 xb = *(const float4*)(agg1 + (size_t)node * 64 + k4 * 4);
                acc[p] = fmaf(xb.x, Wc[k4].x, acc[p]);
                acc[p] = fmaf(xb.y, Wc[k4].y, acc[p]);
                acc[p] = fmaf(xb.z, Wc[k4].z, acc[p]);
                acc[p] = fmaf(xb.w, Wc[k4].w, acc[p]);
            }
        }
        #pragma unroll
        for (int p = 0; p < G2_P; ++p) {
            int node = nodeBase + p;
            if (node < n && lane < 40)
                h2[(size_t)node * H2S_STRIDE + lane] = __float2bfloat16(acc[p] * dinv[node]);
        }
    }
}

// ================= gather layer 2 + fused log_softmax =================

__global__ __launch_bounds__(256) void gather2_kernel(const __hip_bfloat16* __restrict__ h2s,
        const int* __restrict__ rowstart, const int* __restrict__ csr_src,
        const float* __restrict__ dinv, const float* __restrict__ b,
        float* __restrict__ out, int n) {
    int tid = threadIdx.x;
    int node = blockIdx.x * 4 + (tid >> 6);
    int lane = tid & 63;
    if (node >= n) return;
    int feat = (lane < 40) ? lane : 0;   // lanes 40..63 shadow feature 0 (same line)
    float acc = __bfloat162float(h2s[(size_t)node * H2S_STRIDE + feat]);
    int beg = rowstart[node], end = rowstart[node + 1];
    for (int c = beg; c < end; c += 64) {
        int m = min(64, end - c);
        int myE = (lane < m) ? csr_src[c + lane] : 0;
        for (int j = 0; j < m; ++j) {
            int s = __shfl(myE, j);
            acc += __bfloat162float(h2s[(size_t)s * H2S_STRIDE + feat]);
        }
    }
    float v = (lane < 40) ? acc * dinv[node] + b[lane] : -INFINITY;
    float mx = v;
    #pragma unroll
    for (int off = 32; off; off >>= 1) mx = fmaxf(mx, __shfl_xor(mx, off));
    float ex = (lane < 40) ? expf(v - mx) : 0.0f;
    float sm = ex;
    #pragma unroll
    for (int off = 32; off; off >>= 1) sm += __shfl_xor(sm, off);
    if (lane < 40) out[(size_t)node * 40 + lane] = v - mx - logf(sm);
}

extern "C" void kernel_launch(void* const* d_in, const int* in_sizes, int n_in,
                              void* d_out, int out_size, void* d_ws, size_t ws_size,
                              hipStream_t stream) {
    const float* x  = (const float*)d_in[0];
    const int*   ei = (const int*)d_in[1];
    const float* W1 = (const float*)d_in[2];
    const float* b1 = (const float*)d_in[3];
    const float* W2 = (const float*)d_in[4];
    const float* b2 = (const float*)d_in[5];
    float* out = (float*)d_out;

    int N = in_sizes[0] / FIN;     // 100000
    int E = in_sizes[1] / 2;       // 800000
    const int* src = ei;
    const int* dst = ei + E;

    char* ws = (char*)d_ws;
    size_t off = 0;
    auto alloc = [&](size_t bytes) {
        void* p = ws + off;
        off = (off + bytes + 255) & ~(size_t)255;
        return p;
    };
    int nb = (N + 1023) / 1024;    // 98 scan blocks
    unsigned int*    deg       = (unsigned int*)alloc((size_t)N * 4);
    float*           dinv      = (float*)alloc((size_t)N * 4);
    int*             rowstart  = (int*)alloc((size_t)(N + 1) * 4);
    int*             cursor    = (int*)alloc((size_t)N * 4);
    int*             blocksums = (int*)alloc((size_t)nb * 4);
    int*             csr_src   = (int*)alloc((size_t)E * 4);
    __hip_bfloat16*  h1s       = (__hip_bfloat16*)alloc((size_t)N * FIN * 2);
    float*           agg1      = (float*)alloc((size_t)N * HID * 4);
    __hip_bfloat16*  h2s       = (__hip_bfloat16*)alloc((size_t)N * H2S_STRIDE * 2);

    hipMemsetAsync(deg, 0, (size_t)N * 4, stream);
    count_deg_kernel<<<(E + 255) / 256, 256, 0, stream>>>(dst, deg, E);
    dinv_kernel<<<(N + 255) / 256, 256, 0, stream>>>(deg, dinv, N);
    blk_reduce_kernel<<<nb, 256, 0, stream>>>(deg, blocksums, N);
    scan_blocksums_kernel<<<1, 256, 0, stream>>>(blocksums, nb, rowstart, N);
    local_scan_kernel<<<nb, 256, 0, stream>>>(deg, blocksums, rowstart, cursor, N);
    scatter_edges_kernel<<<(E + 255) / 256, 256, 0, stream>>>(src, dst, rowstart, cursor, csr_src, E);
    gemm1_kernel<<<1024, 256, 0, stream>>>(x, W1, dinv, h1s, N);
    gather1_kernel<<<(N + 3) / 4, 256, 0, stream>>>(h1s, rowstart, csr_src, dinv, b1, agg1, N);
    gemm2_kernel<<<1024, 256, 0, stream>>>(agg1, W2, dinv, h2s, N);
    gather2_kernel<<<(N + 3) / 4, 256, 0, stream>>>(h2s, rowstart, csr_src, dinv, b2, out, N);
}

// Round 5
// 308.143 us; speedup vs baseline: 4.7873x; 1.2054x over previous
//
#include <hip/hip_runtime.h>
#include <hip/hip_bf16.h>
#include <math.h>

#define FIN 64
#define HID 64
#define FOUT 40
#define H2S_STRIDE 64   // bf16 elements; 128 B row stride, one cache line per row

__device__ __forceinline__ float bf_lo(unsigned u) { return __uint_as_float(u << 16); }
__device__ __forceinline__ float bf_hi(unsigned u) { return __uint_as_float(u & 0xFFFF0000u); }

// ================= degree =================

__global__ void count_deg_kernel(const int* __restrict__ dst, unsigned int* __restrict__ deg, int E) {
    int e = blockIdx.x * blockDim.x + threadIdx.x;
    if (e < E) atomicAdd(&deg[dst[e]], 1u);
}

// ================= CSR build: prefix sum over degrees =================

__global__ __launch_bounds__(256) void blk_reduce_kernel(const unsigned int* __restrict__ deg,
        int* __restrict__ blocksums, int n) {
    int tid = threadIdx.x;
    int base = blockIdx.x * 1024;
    int s = 0;
    #pragma unroll
    for (int j = 0; j < 4; ++j) {
        int i = base + j * 256 + tid;
        if (i < n) s += (int)deg[i];
    }
    #pragma unroll
    for (int off = 1; off < 64; off <<= 1) s += __shfl_xor(s, off);
    __shared__ int wsum[4];
    if ((tid & 63) == 0) wsum[tid >> 6] = s;
    __syncthreads();
    if (tid == 0) blocksums[blockIdx.x] = wsum[0] + wsum[1] + wsum[2] + wsum[3];
}

__global__ void scan_blocksums_kernel(int* __restrict__ blocksums, int nb,
        int* __restrict__ rowstart, int n) {
    __shared__ int buf[1024];
    int tid = threadIdx.x;
    for (int i = tid; i < nb; i += 256) buf[i] = blocksums[i];
    __syncthreads();
    if (tid == 0) {
        int run = 0;
        for (int i = 0; i < nb; ++i) { int v = buf[i]; buf[i] = run; run += v; }
        rowstart[n] = run;   // == E
    }
    __syncthreads();
    for (int i = tid; i < nb; i += 256) blocksums[i] = buf[i];
}

// Local exclusive scan + rowstart + cursor zero + fused dinv = rsqrt(deg+1).
__global__ __launch_bounds__(256) void local_scan_kernel(const unsigned int* __restrict__ deg,
        const int* __restrict__ blockoffs, int* __restrict__ rowstart,
        int* __restrict__ cursor, float* __restrict__ dinv, int n) {
    int tid = threadIdx.x;
    int lane = tid & 63;
    int wid = tid >> 6;
    int base = blockIdx.x * 1024 + tid * 4;
    int v0 = 0, v1 = 0, v2 = 0, v3 = 0;
    if (base + 3 < n) {
        uint4 u = *(const uint4*)(deg + base);
        v0 = u.x; v1 = u.y; v2 = u.z; v3 = u.w;
    } else {
        if (base + 0 < n) v0 = deg[base + 0];
        if (base + 1 < n) v1 = deg[base + 1];
        if (base + 2 < n) v2 = deg[base + 2];
    }
    int tsum = v0 + v1 + v2 + v3;
    int incl = tsum;
    #pragma unroll
    for (int off = 1; off < 64; off <<= 1) {
        int t = __shfl_up(incl, off);
        if (lane >= off) incl += t;
    }
    int excl = incl - tsum;
    __shared__ int wtot[4];
    if (lane == 63) wtot[wid] = incl;
    __syncthreads();
    int woff = 0;
    for (int w = 0; w < wid; ++w) woff += wtot[w];
    int run = blockoffs[blockIdx.x] + woff + excl;
    int r0 = run, r1 = run + v0, r2 = run + v0 + v1, r3 = run + v0 + v1 + v2;
    if (base + 3 < n) {
        *(int4*)(rowstart + base) = make_int4(r0, r1, r2, r3);
        *(int4*)(cursor + base) = make_int4(0, 0, 0, 0);
        *(float4*)(dinv + base) = make_float4(rsqrtf(v0 + 1.0f), rsqrtf(v1 + 1.0f),
                                              rsqrtf(v2 + 1.0f), rsqrtf(v3 + 1.0f));
    } else {
        if (base + 0 < n) { rowstart[base + 0] = r0; cursor[base + 0] = 0; dinv[base + 0] = rsqrtf(v0 + 1.0f); }
        if (base + 1 < n) { rowstart[base + 1] = r1; cursor[base + 1] = 0; dinv[base + 1] = rsqrtf(v1 + 1.0f); }
        if (base + 2 < n) { rowstart[base + 2] = r2; cursor[base + 2] = 0; dinv[base + 2] = rsqrtf(v2 + 1.0f); }
    }
}

__global__ void scatter_edges_kernel(const int* __restrict__ src, const int* __restrict__ dst,
        const int* __restrict__ rowstart, int* __restrict__ cursor,
        int* __restrict__ csr_src, int E) {
    int e = blockIdx.x * blockDim.x + threadIdx.x;
    if (e >= E) return;
    int d = dst[e];
    int pos = rowstart[d] + atomicAdd(&cursor[d], 1);
    csr_src[pos] = src[e];
}

// ================= layer 1 GEMM: h1s = bf16( (x @ W1) * dinv[node] ) =================

#define G1_P 8

__global__ __launch_bounds__(256) void gemm1_kernel(const float* __restrict__ x,
        const float* __restrict__ W, const float* __restrict__ dinv,
        __hip_bfloat16* __restrict__ h, int n) {
    int lane = threadIdx.x & 63;
    int gwave = (blockIdx.x * 256 + threadIdx.x) >> 6;
    int nwaves = gridDim.x * 4;
    float4 Wc[16];
    #pragma unroll
    for (int k4 = 0; k4 < 16; ++k4) {
        Wc[k4].x = W[(k4 * 4 + 0) * 64 + lane];
        Wc[k4].y = W[(k4 * 4 + 1) * 64 + lane];
        Wc[k4].z = W[(k4 * 4 + 2) * 64 + lane];
        Wc[k4].w = W[(k4 * 4 + 3) * 64 + lane];
    }
    int ntiles = (n + G1_P - 1) / G1_P;
    for (int tile = gwave; tile < ntiles; tile += nwaves) {
        int nodeBase = __builtin_amdgcn_readfirstlane(tile * G1_P);
        float acc[G1_P];
        #pragma unroll
        for (int p = 0; p < G1_P; ++p) acc[p] = 0.0f;
        #pragma unroll
        for (int k4 = 0; k4 < 16; ++k4) {
            #pragma unroll
            for (int p = 0; p < G1_P; ++p) {
                int node = nodeBase + p;
                if (node >= n) node = n - 1;
                float4 xb = *(const float4*)(x + (size_t)node * 64 + k4 * 4);
                acc[p] = fmaf(xb.x, Wc[k4].x, acc[p]);
                acc[p] = fmaf(xb.y, Wc[k4].y, acc[p]);
                acc[p] = fmaf(xb.z, Wc[k4].z, acc[p]);
                acc[p] = fmaf(xb.w, Wc[k4].w, acc[p]);
            }
        }
        #pragma unroll
        for (int p = 0; p < G1_P; ++p) {
            int node = nodeBase + p;
            if (node < n) h[(size_t)node * 64 + lane] = __float2bfloat16(acc[p] * dinv[node]);
        }
    }
}

// ================= gather layer 1 =================
// agg1[d] = relu( (h1s[d] + sum_{e->d} h1s[src]) * dinv[d] + b1 )
// One wave per node; lane holds a bf16x2 feature pair; half-waves cover 2 edges
// per load; unroll x2 -> 4 edges/iter, 2 loads in flight, 4 fp32 acc chains.
// Uniform csr_src reads -> scalar loads (no shfl in the hot loop).

__global__ __launch_bounds__(256) void gather1_kernel(const __hip_bfloat16* __restrict__ h1s,
        const int* __restrict__ rowstart, const int* __restrict__ csr_src,
        const float* __restrict__ dinv, const float* __restrict__ b,
        float* __restrict__ agg1, int n) {
    int tid = threadIdx.x;
    int node_nu = blockIdx.x * 4 + (tid >> 6);
    if (node_nu >= n) return;
    int node = __builtin_amdgcn_readfirstlane(node_nu);
    int lane = tid & 63;
    int half = lane >> 5;          // 0 or 1
    int hl = lane & 31;            // feature-pair index 0..31
    const unsigned* h1u = (const unsigned*)h1s;   // 32 uints per row
    unsigned u_self = h1u[(size_t)node * 32 + hl];
    int beg = rowstart[node], end = rowstart[node + 1];
    float aAl = 0.f, aAh = 0.f, aBl = 0.f, aBh = 0.f;
    int c = beg;
    for (; c + 4 <= end; c += 4) {
        int s0 = csr_src[c + 0], s1 = csr_src[c + 1];   // uniform -> s_load
        int s2 = csr_src[c + 2], s3 = csr_src[c + 3];
        int sA = half ? s1 : s0;
        int sB = half ? s3 : s2;
        unsigned uA = h1u[(size_t)sA * 32 + hl];
        unsigned uB = h1u[(size_t)sB * 32 + hl];
        aAl += bf_lo(uA); aAh += bf_hi(uA);
        aBl += bf_lo(uB); aBh += bf_hi(uB);
    }
    if (c + 2 <= end) {
        int s0 = csr_src[c + 0], s1 = csr_src[c + 1];
        int sA = half ? s1 : s0;
        unsigned uA = h1u[(size_t)sA * 32 + hl];
        aAl += bf_lo(uA); aAh += bf_hi(uA);
        c += 2;
    }
    if (c < end) {
        int s0 = csr_src[c];
        unsigned uA = h1u[(size_t)s0 * 32 + hl];
        if (half == 0) { aAl += bf_lo(uA); aAh += bf_hi(uA); }
    }
    float flo = aAl + aBl;
    float fhi = aAh + aBh;
    flo += __shfl_xor(flo, 32);    // combine the two half-waves
    fhi += __shfl_xor(fhi, 32);
    flo += bf_lo(u_self);
    fhi += bf_hi(u_self);
    float dv = dinv[node];
    float2 bb = *(const float2*)(b + 2 * hl);
    float vlo = fmaxf(flo * dv + bb.x, 0.0f);
    float vhi = fmaxf(fhi * dv + bb.y, 0.0f);
    if (lane < 32)
        *(float2*)(agg1 + (size_t)node * 64 + 2 * hl) = make_float2(vlo, vhi);
}

// ================= layer 2 GEMM: h2s = bf16( (agg1 @ W2) * dinv[node] ) =================

#define G2_P 8

__global__ __launch_bounds__(256) void gemm2_kernel(const float* __restrict__ agg1,
        const float* __restrict__ W, const float* __restrict__ dinv,
        __hip_bfloat16* __restrict__ h2, int n) {
    int lane = threadIdx.x & 63;
    int col = (lane < 40) ? lane : 39;
    int gwave = (blockIdx.x * 256 + threadIdx.x) >> 6;
    int nwaves = gridDim.x * 4;
    float4 Wc[16];
    #pragma unroll
    for (int k4 = 0; k4 < 16; ++k4) {
        Wc[k4].x = W[(k4 * 4 + 0) * 40 + col];
        Wc[k4].y = W[(k4 * 4 + 1) * 40 + col];
        Wc[k4].z = W[(k4 * 4 + 2) * 40 + col];
        Wc[k4].w = W[(k4 * 4 + 3) * 40 + col];
    }
    int ntiles = (n + G2_P - 1) / G2_P;
    for (int tile = gwave; tile < ntiles; tile += nwaves) {
        int nodeBase = __builtin_amdgcn_readfirstlane(tile * G2_P);
        float acc[G2_P];
        #pragma unroll
        for (int p = 0; p < G2_P; ++p) acc[p] = 0.0f;
        #pragma unroll
        for (int k4 = 0; k4 < 16; ++k4) {
            #pragma unroll
            for (int p = 0; p < G2_P; ++p) {
                int node = nodeBase + p;
                if (node >= n) node = n - 1;
                float4 xb = *(const float4*)(agg1 + (size_t)node * 64 + k4 * 4);
                acc[p] = fmaf(xb.x, Wc[k4].x, acc[p]);
                acc[p] = fmaf(xb.y, Wc[k4].y, acc[p]);
                acc[p] = fmaf(xb.z, Wc[k4].z, acc[p]);
                acc[p] = fmaf(xb.w, Wc[k4].w, acc[p]);
            }
        }
        #pragma unroll
        for (int p = 0; p < G2_P; ++p) {
            int node = nodeBase + p;
            if (node < n && lane < 40)
                h2[(size_t)node * H2S_STRIDE + lane] = __float2bfloat16(acc[p] * dinv[node]);
        }
    }
}

// ================= gather layer 2 + fused log_softmax =================
// Same structure as gather1; 40 features -> pair indices 0..19 active.

__global__ __launch_bounds__(256) void gather2_kernel(const __hip_bfloat16* __restrict__ h2s,
        const int* __restrict__ rowstart, const int* __restrict__ csr_src,
        const float* __restrict__ dinv, const float* __restrict__ b,
        float* __restrict__ out, int n) {
    int tid = threadIdx.x;
    int node_nu = blockIdx.x * 4 + (tid >> 6);
    if (node_nu >= n) return;
    int node = __builtin_amdgcn_readfirstlane(node_nu);
    int lane = tid & 63;
    int half = lane >> 5;
    int hl = lane & 31;
    int hlc = (hl < 20) ? hl : 19;            // clamp into the valid 40-feature region
    const unsigned* h2u = (const unsigned*)h2s;   // 32 uints per padded row
    unsigned u_self = h2u[(size_t)node * 32 + hlc];
    int beg = rowstart[node], end = rowstart[node + 1];
    float aAl = 0.f, aAh = 0.f, aBl = 0.f, aBh = 0.f;
    int c = beg;
    for (; c + 4 <= end; c += 4) {
        int s0 = csr_src[c + 0], s1 = csr_src[c + 1];
        int s2 = csr_src[c + 2], s3 = csr_src[c + 3];
        int sA = half ? s1 : s0;
        int sB = half ? s3 : s2;
        unsigned uA = h2u[(size_t)sA * 32 + hlc];
        unsigned uB = h2u[(size_t)sB * 32 + hlc];
        aAl += bf_lo(uA); aAh += bf_hi(uA);
        aBl += bf_lo(uB); aBh += bf_hi(uB);
    }
    if (c + 2 <= end) {
        int s0 = csr_src[c + 0], s1 = csr_src[c + 1];
        int sA = half ? s1 : s0;
        unsigned uA = h2u[(size_t)sA * 32 + hlc];
        aAl += bf_lo(uA); aAh += bf_hi(uA);
        c += 2;
    }
    if (c < end) {
        int s0 = csr_src[c];
        unsigned uA = h2u[(size_t)s0 * 32 + hlc];
        if (half == 0) { aAl += bf_lo(uA); aAh += bf_hi(uA); }
    }
    float flo = aAl + aBl;
    float fhi = aAh + aBh;
    flo += __shfl_xor(flo, 32);
    fhi += __shfl_xor(fhi, 32);
    flo += bf_lo(u_self);
    fhi += bf_hi(u_self);
    float dv = dinv[node];
    float2 bb = *(const float2*)(b + 2 * hlc);
    float vlo = flo * dv + bb.x;
    float vhi = fhi * dv + bb.y;
    // log-softmax over 40 features (pairs in lanes hl<20, duplicated across halves)
    float mx = (hl < 20) ? fmaxf(vlo, vhi) : -INFINITY;
    #pragma unroll
    for (int off = 16; off; off >>= 1) mx = fmaxf(mx, __shfl_xor(mx, off));
    float e0 = (hl < 20) ? expf(vlo - mx) : 0.0f;
    float e1 = (hl < 20) ? expf(vhi - mx) : 0.0f;
    float sm = e0 + e1;
    #pragma unroll
    for (int off = 16; off; off >>= 1) sm += __shfl_xor(sm, off);
    float ls = mx + logf(sm);
    if (lane < 32 && hl < 20)
        *(float2*)(out + (size_t)node * 40 + 2 * hl) = make_float2(vlo - ls, vhi - ls);
}

extern "C" void kernel_launch(void* const* d_in, const int* in_sizes, int n_in,
                              void* d_out, int out_size, void* d_ws, size_t ws_size,
                              hipStream_t stream) {
    const float* x  = (const float*)d_in[0];
    const int*   ei = (const int*)d_in[1];
    const float* W1 = (const float*)d_in[2];
    const float* b1 = (const float*)d_in[3];
    const float* W2 = (const float*)d_in[4];
    const float* b2 = (const float*)d_in[5];
    float* out = (float*)d_out;

    int N = in_sizes[0] / FIN;     // 100000
    int E = in_sizes[1] / 2;       // 800000
    const int* src = ei;
    const int* dst = ei + E;

    char* ws = (char*)d_ws;
    size_t off = 0;
    auto alloc = [&](size_t bytes) {
        void* p = ws + off;
        off = (off + bytes + 255) & ~(size_t)255;
        return p;
    };
    int nb = (N + 1023) / 1024;    // 98 scan blocks
    unsigned int*    deg       = (unsigned int*)alloc((size_t)N * 4);
    float*           dinv      = (float*)alloc((size_t)N * 4);
    int*             rowstart  = (int*)alloc((size_t)(N + 1) * 4);
    int*             cursor    = (int*)alloc((size_t)N * 4);
    int*             blocksums = (int*)alloc((size_t)nb * 4);
    int*             csr_src   = (int*)alloc((size_t)E * 4);
    __hip_bfloat16*  h1s       = (__hip_bfloat16*)alloc((size_t)N * FIN * 2);
    float*           agg1      = (float*)alloc((size_t)N * HID * 4);
    __hip_bfloat16*  h2s       = (__hip_bfloat16*)alloc((size_t)N * H2S_STRIDE * 2);

    hipMemsetAsync(deg, 0, (size_t)N * 4, stream);
    count_deg_kernel<<<(E + 255) / 256, 256, 0, stream>>>(dst, deg, E);
    blk_reduce_kernel<<<nb, 256, 0, stream>>>(deg, blocksums, N);
    scan_blocksums_kernel<<<1, 256, 0, stream>>>(blocksums, nb, rowstart, N);
    local_scan_kernel<<<nb, 256, 0, stream>>>(deg, blocksums, rowstart, cursor, dinv, N);
    scatter_edges_kernel<<<(E + 255) / 256, 256, 0, stream>>>(src, dst, rowstart, cursor, csr_src, E);
    gemm1_kernel<<<1024, 256, 0, stream>>>(x, W1, dinv, h1s, N);
    gather1_kernel<<<(N + 3) / 4, 256, 0, stream>>>(h1s, rowstart, csr_src, dinv, b1, agg1, N);
    gemm2_kernel<<<1024, 256, 0, stream>>>(agg1, W2, dinv, h2s, N);
    gather2_kernel<<<(N + 3) / 4, 256, 0, stream>>>(h2s, rowstart, csr_src, dinv, b2, out, N);
}

// Round 6
// 263.725 us; speedup vs baseline: 5.5937x; 1.1684x over previous
//
#include <hip/hip_runtime.h>
#include <hip/hip_bf16.h>
#include <math.h>

#define FIN 64
#define HID 64
#define FOUT 40
#define H2S_STRIDE 64   // bf16 elements; 128 B row stride, one cache line per row
#define LDSU 36         // uint stride per staged LDS row (144 B): pad breaks conflicts

typedef __attribute__((ext_vector_type(8))) short short8;
typedef __attribute__((ext_vector_type(4))) float f32x4;

__device__ __forceinline__ float bf_lo(unsigned u) { return __uint_as_float(u << 16); }
__device__ __forceinline__ float bf_hi(unsigned u) { return __uint_as_float(u & 0xFFFF0000u); }

// round-to-nearest-even fp32 -> bf16 bits
__device__ __forceinline__ unsigned short bfbits(float f) {
    unsigned u = __float_as_uint(f);
    u += 0x7FFFu + ((u >> 16) & 1u);
    return (unsigned short)(u >> 16);
}
__device__ __forceinline__ unsigned pk_bf16(float lo, float hi) {
    unsigned a = __float_as_uint(lo), b = __float_as_uint(hi);
    a += 0x7FFFu + ((a >> 16) & 1u);
    b += 0x7FFFu + ((b >> 16) & 1u);
    return (a >> 16) | (b & 0xFFFF0000u);
}

// ================= degree =================

__global__ void count_deg_kernel(const int* __restrict__ dst, unsigned int* __restrict__ deg, int E) {
    int e = blockIdx.x * blockDim.x + threadIdx.x;
    if (e < E) atomicAdd(&deg[dst[e]], 1u);
}

// ================= CSR build: prefix sum over degrees =================

__global__ __launch_bounds__(256) void blk_reduce_kernel(const unsigned int* __restrict__ deg,
        int* __restrict__ blocksums, int n) {
    int tid = threadIdx.x;
    int base = blockIdx.x * 1024;
    int s = 0;
    #pragma unroll
    for (int j = 0; j < 4; ++j) {
        int i = base + j * 256 + tid;
        if (i < n) s += (int)deg[i];
    }
    #pragma unroll
    for (int off = 1; off < 64; off <<= 1) s += __shfl_xor(s, off);
    __shared__ int wsum[4];
    if ((tid & 63) == 0) wsum[tid >> 6] = s;
    __syncthreads();
    if (tid == 0) blocksums[blockIdx.x] = wsum[0] + wsum[1] + wsum[2] + wsum[3];
}

__global__ void scan_blocksums_kernel(int* __restrict__ blocksums, int nb,
        int* __restrict__ rowstart, int n) {
    __shared__ int buf[1024];
    int tid = threadIdx.x;
    for (int i = tid; i < nb; i += 256) buf[i] = blocksums[i];
    __syncthreads();
    if (tid == 0) {
        int run = 0;
        for (int i = 0; i < nb; ++i) { int v = buf[i]; buf[i] = run; run += v; }
        rowstart[n] = run;   // == E
    }
    __syncthreads();
    for (int i = tid; i < nb; i += 256) blocksums[i] = buf[i];
}

// Local exclusive scan + rowstart + cursor zero + fused dinv = rsqrt(deg+1).
__global__ __launch_bounds__(256) void local_scan_kernel(const unsigned int* __restrict__ deg,
        const int* __restrict__ blockoffs, int* __restrict__ rowstart,
        int* __restrict__ cursor, float* __restrict__ dinv, int n) {
    int tid = threadIdx.x;
    int lane = tid & 63;
    int wid = tid >> 6;
    int base = blockIdx.x * 1024 + tid * 4;
    int v0 = 0, v1 = 0, v2 = 0, v3 = 0;
    if (base + 3 < n) {
        uint4 u = *(const uint4*)(deg + base);
        v0 = u.x; v1 = u.y; v2 = u.z; v3 = u.w;
    } else {
        if (base + 0 < n) v0 = deg[base + 0];
        if (base + 1 < n) v1 = deg[base + 1];
        if (base + 2 < n) v2 = deg[base + 2];
    }
    int tsum = v0 + v1 + v2 + v3;
    int incl = tsum;
    #pragma unroll
    for (int off = 1; off < 64; off <<= 1) {
        int t = __shfl_up(incl, off);
        if (lane >= off) incl += t;
    }
    int excl = incl - tsum;
    __shared__ int wtot[4];
    if (lane == 63) wtot[wid] = incl;
    __syncthreads();
    int woff = 0;
    for (int w = 0; w < wid; ++w) woff += wtot[w];
    int run = blockoffs[blockIdx.x] + woff + excl;
    int r0 = run, r1 = run + v0, r2 = run + v0 + v1, r3 = run + v0 + v1 + v2;
    if (base + 3 < n) {
        *(int4*)(rowstart + base) = make_int4(r0, r1, r2, r3);
        *(int4*)(cursor + base) = make_int4(0, 0, 0, 0);
        *(float4*)(dinv + base) = make_float4(rsqrtf(v0 + 1.0f), rsqrtf(v1 + 1.0f),
                                              rsqrtf(v2 + 1.0f), rsqrtf(v3 + 1.0f));
    } else {
        if (base + 0 < n) { rowstart[base + 0] = r0; cursor[base + 0] = 0; dinv[base + 0] = rsqrtf(v0 + 1.0f); }
        if (base + 1 < n) { rowstart[base + 1] = r1; cursor[base + 1] = 0; dinv[base + 1] = rsqrtf(v1 + 1.0f); }
        if (base + 2 < n) { rowstart[base + 2] = r2; cursor[base + 2] = 0; dinv[base + 2] = rsqrtf(v2 + 1.0f); }
    }
}

__global__ void scatter_edges_kernel(const int* __restrict__ src, const int* __restrict__ dst,
        const int* __restrict__ rowstart, int* __restrict__ cursor,
        int* __restrict__ csr_src, int E) {
    int e = blockIdx.x * blockDim.x + threadIdx.x;
    if (e >= E) return;
    int d = dst[e];
    int pos = rowstart[d] + atomicAdd(&cursor[d], 1);
    csr_src[pos] = src[e];
}

// ================= layer 1 GEMM (MFMA bf16): h1s = bf16( (x @ W1) * dinv ) =================
// Block = 256 threads / 64 nodes. A-tile staged to LDS as bf16 (144 B row stride).
// Wave w owns nodes [base+16w, base+16w+16); 4 N-tiles x 2 k-steps = 8 MFMAs.

__global__ __launch_bounds__(256) void gemm1_mfma(const float* __restrict__ x,
        const float* __restrict__ W, const float* __restrict__ dinv,
        __hip_bfloat16* __restrict__ h, int n) {
    __shared__ unsigned As[64 * LDSU];
    int tid = threadIdx.x;
    int lane = tid & 63;
    int w = tid >> 6;
    int q = lane >> 4;        // 0..3 k-block / row-quad
    int c = lane & 15;        // col within tile
    int nodeBase = blockIdx.x * 64;

    // stage x (fp32) -> bf16 LDS
    #pragma unroll
    for (int i = 0; i < 4; ++i) {
        int fidx = tid + 256 * i;          // float4 index 0..1023
        int row = fidx >> 4, c4 = fidx & 15;
        int node = nodeBase + row; if (node >= n) node = n - 1;
        float4 v = *(const float4*)(x + (size_t)node * 64 + c4 * 4);
        As[row * LDSU + c4 * 2 + 0] = pk_bf16(v.x, v.y);
        As[row * LDSU + c4 * 2 + 1] = pk_bf16(v.z, v.w);
    }
    // B-frags: W1 64x64 fp32 -> bf16 registers. B[k = kk*32+q*8+j][n = nt*16+c]
    short8 Bf[4][2];
    #pragma unroll
    for (int nt = 0; nt < 4; ++nt)
        #pragma unroll
        for (int kk = 0; kk < 2; ++kk)
            #pragma unroll
            for (int j = 0; j < 8; ++j)
                Bf[nt][kk][j] = (short)bfbits(W[(kk * 32 + q * 8 + j) * 64 + nt * 16 + c]);
    __syncthreads();

    f32x4 acc[4];
    #pragma unroll
    for (int nt = 0; nt < 4; ++nt) acc[nt] = (f32x4){0.f, 0.f, 0.f, 0.f};
    #pragma unroll
    for (int kk = 0; kk < 2; ++kk) {
        // A[m = lane&15][k = kk*32 + q*8 + j] : 16 B ds_read_b128
        short8 a = *(const short8*)&As[(w * 16 + c) * LDSU + kk * 16 + q * 4];
        #pragma unroll
        for (int nt = 0; nt < 4; ++nt)
            acc[nt] = __builtin_amdgcn_mfma_f32_16x16x32_bf16(a, Bf[nt][kk], acc[nt], 0, 0, 0);
    }
    // C layout: col = lane&15, row = q*4 + reg
    unsigned short* hu = (unsigned short*)h;
    #pragma unroll
    for (int r = 0; r < 4; ++r) {
        int node = nodeBase + w * 16 + q * 4 + r;
        if (node < n) {
            float dv = dinv[node];
            #pragma unroll
            for (int nt = 0; nt < 4; ++nt)
                hu[(size_t)node * 64 + nt * 16 + c] = bfbits(acc[nt][r] * dv);
        }
    }
}

// ================= gather layer 1 =================
// agg1b[d] = bf16( relu( (h1s[d] + sum_{e->d} h1s[src]) * dinv[d] + b1 ) )

__global__ __launch_bounds__(256) void gather1_kernel(const __hip_bfloat16* __restrict__ h1s,
        const int* __restrict__ rowstart, const int* __restrict__ csr_src,
        const float* __restrict__ dinv, const float* __restrict__ b,
        __hip_bfloat16* __restrict__ agg1, int n) {
    int tid = threadIdx.x;
    int node_nu = blockIdx.x * 4 + (tid >> 6);
    if (node_nu >= n) return;
    int node = __builtin_amdgcn_readfirstlane(node_nu);
    int lane = tid & 63;
    int half = lane >> 5;          // 0 or 1
    int hl = lane & 31;            // feature-pair index 0..31
    const unsigned* h1u = (const unsigned*)h1s;   // 32 uints per row
    unsigned u_self = h1u[(size_t)node * 32 + hl];
    int beg = rowstart[node], end = rowstart[node + 1];
    float aAl = 0.f, aAh = 0.f, aBl = 0.f, aBh = 0.f;
    int c = beg;
    for (; c + 4 <= end; c += 4) {
        int s0 = csr_src[c + 0], s1 = csr_src[c + 1];   // uniform -> s_load
        int s2 = csr_src[c + 2], s3 = csr_src[c + 3];
        int sA = half ? s1 : s0;
        int sB = half ? s3 : s2;
        unsigned uA = h1u[(size_t)sA * 32 + hl];
        unsigned uB = h1u[(size_t)sB * 32 + hl];
        aAl += bf_lo(uA); aAh += bf_hi(uA);
        aBl += bf_lo(uB); aBh += bf_hi(uB);
    }
    if (c + 2 <= end) {
        int s0 = csr_src[c + 0], s1 = csr_src[c + 1];
        int sA = half ? s1 : s0;
        unsigned uA = h1u[(size_t)sA * 32 + hl];
        aAl += bf_lo(uA); aAh += bf_hi(uA);
        c += 2;
    }
    if (c < end) {
        int s0 = csr_src[c];
        unsigned uA = h1u[(size_t)s0 * 32 + hl];
        if (half == 0) { aAl += bf_lo(uA); aAh += bf_hi(uA); }
    }
    float flo = aAl + aBl;
    float fhi = aAh + aBh;
    flo += __shfl_xor(flo, 32);    // combine the two half-waves
    fhi += __shfl_xor(fhi, 32);
    flo += bf_lo(u_self);
    fhi += bf_hi(u_self);
    float dv = dinv[node];
    float2 bb = *(const float2*)(b + 2 * hl);
    float vlo = fmaxf(flo * dv + bb.x, 0.0f);
    float vhi = fmaxf(fhi * dv + bb.y, 0.0f);
    if (lane < 32)
        ((unsigned*)agg1)[(size_t)node * 32 + hl] = pk_bf16(vlo, vhi);
}

// ================= layer 2 GEMM (MFMA bf16): h2s = bf16( (agg1b @ W2) * dinv ) =================
// A already bf16 (stride 32 uints/row). 3 N-tiles cover 40 cols (last masked).

__global__ __launch_bounds__(256) void gemm2_mfma(const __hip_bfloat16* __restrict__ agg1b,
        const float* __restrict__ W, const float* __restrict__ dinv,
        __hip_bfloat16* __restrict__ h2, int n) {
    __shared__ unsigned As[64 * LDSU];
    int tid = threadIdx.x;
    int lane = tid & 63;
    int w = tid >> 6;
    int q = lane >> 4;
    int c = lane & 15;
    int nodeBase = blockIdx.x * 64;
    const unsigned* a1u = (const unsigned*)agg1b;

    // stage agg1b (bf16) -> LDS (64 rows x 32 uints, padded stride)
    #pragma unroll
    for (int i = 0; i < 8; ++i) {
        int uidx = tid + 256 * i;          // 0..2047
        int row = uidx >> 5, col = uidx & 31;
        int node = nodeBase + row; if (node >= n) node = n - 1;
        As[row * LDSU + col] = a1u[(size_t)node * 32 + col];
    }
    // B-frags: W2 64x40 fp32. invalid cols (>=40) -> 0
    short8 Bf[3][2];
    #pragma unroll
    for (int nt = 0; nt < 3; ++nt) {
        int nn = nt * 16 + c;
        bool valid = (nn < 40);
        #pragma unroll
        for (int kk = 0; kk < 2; ++kk)
            #pragma unroll
            for (int j = 0; j < 8; ++j)
                Bf[nt][kk][j] = valid ? (short)bfbits(W[(kk * 32 + q * 8 + j) * 40 + nn]) : (short)0;
    }
    __syncthreads();

    f32x4 acc[3];
    #pragma unroll
    for (int nt = 0; nt < 3; ++nt) acc[nt] = (f32x4){0.f, 0.f, 0.f, 0.f};
    #pragma unroll
    for (int kk = 0; kk < 2; ++kk) {
        short8 a = *(const short8*)&As[(w * 16 + c) * LDSU + kk * 16 + q * 4];
        #pragma unroll
        for (int nt = 0; nt < 3; ++nt)
            acc[nt] = __builtin_amdgcn_mfma_f32_16x16x32_bf16(a, Bf[nt][kk], acc[nt], 0, 0, 0);
    }
    unsigned short* hu = (unsigned short*)h2;
    #pragma unroll
    for (int r = 0; r < 4; ++r) {
        int node = nodeBase + w * 16 + q * 4 + r;
        if (node < n) {
            float dv = dinv[node];
            #pragma unroll
            for (int nt = 0; nt < 3; ++nt) {
                int nn = nt * 16 + c;
                if (nn < 40)
                    hu[(size_t)node * H2S_STRIDE + nn] = bfbits(acc[nt][r] * dv);
            }
        }
    }
}

// ================= gather layer 2 + fused log_softmax =================

__global__ __launch_bounds__(256) void gather2_kernel(const __hip_bfloat16* __restrict__ h2s,
        const int* __restrict__ rowstart, const int* __restrict__ csr_src,
        const float* __restrict__ dinv, const float* __restrict__ b,
        float* __restrict__ out, int n) {
    int tid = threadIdx.x;
    int node_nu = blockIdx.x * 4 + (tid >> 6);
    if (node_nu >= n) return;
    int node = __builtin_amdgcn_readfirstlane(node_nu);
    int lane = tid & 63;
    int half = lane >> 5;
    int hl = lane & 31;
    int hlc = (hl < 20) ? hl : 19;            // clamp into the valid 40-feature region
    const unsigned* h2u = (const unsigned*)h2s;   // 32 uints per padded row
    unsigned u_self = h2u[(size_t)node * 32 + hlc];
    int beg = rowstart[node], end = rowstart[node + 1];
    float aAl = 0.f, aAh = 0.f, aBl = 0.f, aBh = 0.f;
    int c = beg;
    for (; c + 4 <= end; c += 4) {
        int s0 = csr_src[c + 0], s1 = csr_src[c + 1];
        int s2 = csr_src[c + 2], s3 = csr_src[c + 3];
        int sA = half ? s1 : s0;
        int sB = half ? s3 : s2;
        unsigned uA = h2u[(size_t)sA * 32 + hlc];
        unsigned uB = h2u[(size_t)sB * 32 + hlc];
        aAl += bf_lo(uA); aAh += bf_hi(uA);
        aBl += bf_lo(uB); aBh += bf_hi(uB);
    }
    if (c + 2 <= end) {
        int s0 = csr_src[c + 0], s1 = csr_src[c + 1];
        int sA = half ? s1 : s0;
        unsigned uA = h2u[(size_t)sA * 32 + hlc];
        aAl += bf_lo(uA); aAh += bf_hi(uA);
        c += 2;
    }
    if (c < end) {
        int s0 = csr_src[c];
        unsigned uA = h2u[(size_t)s0 * 32 + hlc];
        if (half == 0) { aAl += bf_lo(uA); aAh += bf_hi(uA); }
    }
    float flo = aAl + aBl;
    float fhi = aAh + aBh;
    flo += __shfl_xor(flo, 32);
    fhi += __shfl_xor(fhi, 32);
    flo += bf_lo(u_self);
    fhi += bf_hi(u_self);
    float dv = dinv[node];
    float2 bb = *(const float2*)(b + 2 * hlc);
    float vlo = flo * dv + bb.x;
    float vhi = fhi * dv + bb.y;
    // log-softmax over 40 features (pairs in lanes hl<20, duplicated across halves)
    float mx = (hl < 20) ? fmaxf(vlo, vhi) : -INFINITY;
    #pragma unroll
    for (int off = 16; off; off >>= 1) mx = fmaxf(mx, __shfl_xor(mx, off));
    float e0 = (hl < 20) ? expf(vlo - mx) : 0.0f;
    float e1 = (hl < 20) ? expf(vhi - mx) : 0.0f;
    float sm = e0 + e1;
    #pragma unroll
    for (int off = 16; off; off >>= 1) sm += __shfl_xor(sm, off);
    float ls = mx + logf(sm);
    if (lane < 32 && hl < 20)
        *(float2*)(out + (size_t)node * 40 + 2 * hl) = make_float2(vlo - ls, vhi - ls);
}

extern "C" void kernel_launch(void* const* d_in, const int* in_sizes, int n_in,
                              void* d_out, int out_size, void* d_ws, size_t ws_size,
                              hipStream_t stream) {
    const float* x  = (const float*)d_in[0];
    const int*   ei = (const int*)d_in[1];
    const float* W1 = (const float*)d_in[2];
    const float* b1 = (const float*)d_in[3];
    const float* W2 = (const float*)d_in[4];
    const float* b2 = (const float*)d_in[5];
    float* out = (float*)d_out;

    int N = in_sizes[0] / FIN;     // 100000
    int E = in_sizes[1] / 2;       // 800000
    const int* src = ei;
    const int* dst = ei + E;

    char* ws = (char*)d_ws;
    size_t off = 0;
    auto alloc = [&](size_t bytes) {
        void* p = ws + off;
        off = (off + bytes + 255) & ~(size_t)255;
        return p;
    };
    int nb = (N + 1023) / 1024;    // 98 scan blocks
    unsigned int*    deg       = (unsigned int*)alloc((size_t)N * 4);
    float*           dinv      = (float*)alloc((size_t)N * 4);
    int*             rowstart  = (int*)alloc((size_t)(N + 1) * 4);
    int*             cursor    = (int*)alloc((size_t)N * 4);
    int*             blocksums = (int*)alloc((size_t)nb * 4);
    int*             csr_src   = (int*)alloc((size_t)E * 4);
    __hip_bfloat16*  h1s       = (__hip_bfloat16*)alloc((size_t)N * FIN * 2);
    __hip_bfloat16*  agg1b     = (__hip_bfloat16*)alloc((size_t)N * HID * 2);
    __hip_bfloat16*  h2s       = (__hip_bfloat16*)alloc((size_t)N * H2S_STRIDE * 2);

    int gblocks = (N + 63) / 64;   // 1563

    hipMemsetAsync(deg, 0, (size_t)N * 4, stream);
    count_deg_kernel<<<(E + 255) / 256, 256, 0, stream>>>(dst, deg, E);
    blk_reduce_kernel<<<nb, 256, 0, stream>>>(deg, blocksums, N);
    scan_blocksums_kernel<<<1, 256, 0, stream>>>(blocksums, nb, rowstart, N);
    local_scan_kernel<<<nb, 256, 0, stream>>>(deg, blocksums, rowstart, cursor, dinv, N);
    scatter_edges_kernel<<<(E + 255) / 256, 256, 0, stream>>>(src, dst, rowstart, cursor, csr_src, E);
    gemm1_mfma<<<gblocks, 256, 0, stream>>>(x, W1, dinv, h1s, N);
    gather1_kernel<<<(N + 3) / 4, 256, 0, stream>>>(h1s, rowstart, csr_src, dinv, b1, agg1b, N);
    gemm2_mfma<<<gblocks, 256, 0, stream>>>(agg1b, W2, dinv, h2s, N);
    gather2_kernel<<<(N + 3) / 4, 256, 0, stream>>>(h2s, rowstart, csr_src, dinv, b2, out, N);
}

// Round 7
// 200.340 us; speedup vs baseline: 7.3634x; 1.3164x over previous
//
#include <hip/hip_runtime.h>
#include <hip/hip_bf16.h>
#include <math.h>

#define FIN 64
#define HID 64
#define FOUT 40
#define H2S_STRIDE 64   // bf16 elements; 128 B row stride, one cache line per row
#define LDSU 36         // uint stride per staged LDS row (144 B): pad breaks conflicts
#define CCHUNK 4096     // edges per partition block
#define MAXBUCK 400     // LDS histogram capacity (>= nbuck = ceil(N/256))

typedef __attribute__((ext_vector_type(8))) short short8;
typedef __attribute__((ext_vector_type(4))) float f32x4;

__device__ __forceinline__ float bf_lo(unsigned u) { return __uint_as_float(u << 16); }
__device__ __forceinline__ float bf_hi(unsigned u) { return __uint_as_float(u & 0xFFFF0000u); }

// round-to-nearest-even fp32 -> bf16 bits
__device__ __forceinline__ unsigned short bfbits(float f) {
    unsigned u = __float_as_uint(f);
    u += 0x7FFFu + ((u >> 16) & 1u);
    return (unsigned short)(u >> 16);
}
__device__ __forceinline__ unsigned pk_bf16(float lo, float hi) {
    unsigned a = __float_as_uint(lo), b = __float_as_uint(hi);
    a += 0x7FFFu + ((a >> 16) & 1u);
    b += 0x7FFFu + ((b >> 16) & 1u);
    return (a >> 16) | (b & 0xFFFF0000u);
}

// ================= CSR build: two-level counting sort (no global atomics) =================
// bucket = dst >> 8 (256 nodes per bucket). Pack: src (20 bits) | local_dst << 20.

// Pass A: per-(block-chunk) histogram over buckets.
__global__ __launch_bounds__(256) void bucket_hist_kernel(const int* __restrict__ dst,
        int* __restrict__ cnt, int E, int nbuck, int nblkc) {
    __shared__ int hist[MAXBUCK];
    int tid = threadIdx.x;
    for (int i = tid; i < nbuck; i += 256) hist[i] = 0;
    __syncthreads();
    int base = blockIdx.x * CCHUNK;
    int lim = min(CCHUNK, E - base);
    for (int i = tid; i < lim; i += 256)
        atomicAdd(&hist[dst[base + i] >> 8], 1);
    __syncthreads();
    for (int b = tid; b < nbuck; b += 256)
        cnt[b * nblkc + blockIdx.x] = hist[b];
}

// Pass B1: per-bucket exclusive scan over the nblkc block counts; total per bucket.
__global__ __launch_bounds__(256) void bucket_colscan_kernel(int* __restrict__ cnt,
        int* __restrict__ total, int nblkc) {
    int b = blockIdx.x;
    int tid = threadIdx.x, lane = tid & 63, wid = tid >> 6;
    int v = (tid < nblkc) ? cnt[b * nblkc + tid] : 0;
    int incl = v;
    #pragma unroll
    for (int off = 1; off < 64; off <<= 1) {
        int t2 = __shfl_up(incl, off);
        if (lane >= off) incl += t2;
    }
    __shared__ int ws[4];
    if (lane == 63) ws[wid] = incl;
    __syncthreads();
    int woff = 0;
    for (int w2 = 0; w2 < wid; ++w2) woff += ws[w2];
    int excl = woff + incl - v;
    if (tid < nblkc) cnt[b * nblkc + tid] = excl;
    if (tid == 255) total[b] = woff + incl;   // grand total of this bucket
}

// Pass B2: exclusive scan of bucket totals -> bucketStart[0..nbuck]; rowstart[N]=E.
__global__ __launch_bounds__(512) void bucket_scan_kernel(const int* __restrict__ total,
        int* __restrict__ bucketStart, int nbuck, int* __restrict__ rowstart, int N) {
    int tid = threadIdx.x, lane = tid & 63, wid = tid >> 6;
    int v = (tid < nbuck) ? total[tid] : 0;
    int incl = v;
    #pragma unroll
    for (int off = 1; off < 64; off <<= 1) {
        int t2 = __shfl_up(incl, off);
        if (lane >= off) incl += t2;
    }
    __shared__ int ws[8];
    if (lane == 63) ws[wid] = incl;
    __syncthreads();
    int woff = 0;
    for (int w2 = 0; w2 < wid; ++w2) woff += ws[w2];
    int excl = woff + incl - v;
    if (tid <= nbuck) bucketStart[tid] = excl;
    if (tid == nbuck) rowstart[N] = excl;     // == E
}

// Pass C: partition edges into bucket-ordered ebuf (packed). LDS cursors only.
__global__ __launch_bounds__(256) void partition_kernel(const int* __restrict__ src,
        const int* __restrict__ dst, const int* __restrict__ cnt,
        const int* __restrict__ bucketStart, unsigned* __restrict__ ebuf,
        int E, int nbuck, int nblkc) {
    __shared__ int cur[MAXBUCK];
    int tid = threadIdx.x;
    int r = blockIdx.x;
    for (int b = tid; b < nbuck; b += 256)
        cur[b] = bucketStart[b] + cnt[b * nblkc + r];
    __syncthreads();
    int base = r * CCHUNK;
    int lim = min(CCHUNK, E - base);
    for (int i = tid; i < lim; i += 256) {
        int d = dst[base + i];
        int s = src[base + i];
        int b = d >> 8;
        int pos = atomicAdd(&cur[b], 1);       // LDS atomic
        ebuf[pos] = (unsigned)s | ((unsigned)(d & 255) << 20);
    }
}

// Pass D: one block per bucket. Local histogram -> rowstart + dinv; LDS-staged
// counting sort of the bucket's src ids -> coalesced csr_src writes.
__global__ __launch_bounds__(256) void build_csr_kernel(const unsigned* __restrict__ ebuf,
        const int* __restrict__ bucketStart, int* __restrict__ rowstart,
        float* __restrict__ dinv, int* __restrict__ csr_src, int n) {
    __shared__ int hist[256];
    __shared__ int cur[256];
    __shared__ int ws[4];
    __shared__ int stage[4096];
    int b = blockIdx.x, tid = threadIdx.x;
    int base = bucketStart[b];
    int m = bucketStart[b + 1] - base;
    hist[tid] = 0;
    __syncthreads();
    for (int i = tid; i < m; i += 256)
        atomicAdd(&hist[ebuf[base + i] >> 20], 1);
    __syncthreads();
    int deg = hist[tid];
    int lane = tid & 63, wid = tid >> 6;
    int incl = deg;
    #pragma unroll
    for (int off = 1; off < 64; off <<= 1) {
        int t2 = __shfl_up(incl, off);
        if (lane >= off) incl += t2;
    }
    if (lane == 63) ws[wid] = incl;
    __syncthreads();
    int woff = 0;
    for (int w2 = 0; w2 < wid; ++w2) woff += ws[w2];
    int excl = woff + incl - deg;
    int node = b * 256 + tid;
    if (node < n) {
        rowstart[node] = base + excl;
        dinv[node] = rsqrtf((float)deg + 1.0f);
    }
    cur[tid] = excl;
    __syncthreads();
    if (m <= 4096) {
        for (int i = tid; i < m; i += 256) {
            unsigned p = ebuf[base + i];
            int pos = atomicAdd(&cur[p >> 20], 1);
            stage[pos] = (int)(p & 0xFFFFFu);
        }
        __syncthreads();
        for (int i = tid; i < m; i += 256)
            csr_src[base + i] = stage[i];      // coalesced
    } else {                                   // safety fallback (never hit for uniform E/N)
        for (int i = tid; i < m; i += 256) {
            unsigned p = ebuf[base + i];
            int pos = atomicAdd(&cur[p >> 20], 1);
            csr_src[base + pos] = (int)(p & 0xFFFFFu);
        }
    }
}

// ================= layer 1 GEMM (MFMA bf16): h1s = bf16( (x @ W1) * dinv ) =================

__global__ __launch_bounds__(256) void gemm1_mfma(const float* __restrict__ x,
        const float* __restrict__ W, const float* __restrict__ dinv,
        __hip_bfloat16* __restrict__ h, int n) {
    __shared__ unsigned As[64 * LDSU];
    int tid = threadIdx.x;
    int lane = tid & 63;
    int w = tid >> 6;
    int q = lane >> 4;        // 0..3 k-block / row-quad
    int c = lane & 15;        // col within tile
    int nodeBase = blockIdx.x * 64;

    #pragma unroll
    for (int i = 0; i < 4; ++i) {
        int fidx = tid + 256 * i;          // float4 index 0..1023
        int row = fidx >> 4, c4 = fidx & 15;
        int node = nodeBase + row; if (node >= n) node = n - 1;
        float4 v = *(const float4*)(x + (size_t)node * 64 + c4 * 4);
        As[row * LDSU + c4 * 2 + 0] = pk_bf16(v.x, v.y);
        As[row * LDSU + c4 * 2 + 1] = pk_bf16(v.z, v.w);
    }
    short8 Bf[4][2];
    #pragma unroll
    for (int nt = 0; nt < 4; ++nt)
        #pragma unroll
        for (int kk = 0; kk < 2; ++kk)
            #pragma unroll
            for (int j = 0; j < 8; ++j)
                Bf[nt][kk][j] = (short)bfbits(W[(kk * 32 + q * 8 + j) * 64 + nt * 16 + c]);
    __syncthreads();

    f32x4 acc[4];
    #pragma unroll
    for (int nt = 0; nt < 4; ++nt) acc[nt] = (f32x4){0.f, 0.f, 0.f, 0.f};
    #pragma unroll
    for (int kk = 0; kk < 2; ++kk) {
        short8 a = *(const short8*)&As[(w * 16 + c) * LDSU + kk * 16 + q * 4];
        #pragma unroll
        for (int nt = 0; nt < 4; ++nt)
            acc[nt] = __builtin_amdgcn_mfma_f32_16x16x32_bf16(a, Bf[nt][kk], acc[nt], 0, 0, 0);
    }
    unsigned short* hu = (unsigned short*)h;
    #pragma unroll
    for (int r = 0; r < 4; ++r) {
        int node = nodeBase + w * 16 + q * 4 + r;
        if (node < n) {
            float dv = dinv[node];
            #pragma unroll
            for (int nt = 0; nt < 4; ++nt)
                hu[(size_t)node * 64 + nt * 16 + c] = bfbits(acc[nt][r] * dv);
        }
    }
}

// ================= gather layer 1 =================
// agg1b[d] = bf16( relu( (h1s[d] + sum_{e->d} h1s[src]) * dinv[d] + b1 ) )

__global__ __launch_bounds__(256) void gather1_kernel(const __hip_bfloat16* __restrict__ h1s,
        const int* __restrict__ rowstart, const int* __restrict__ csr_src,
        const float* __restrict__ dinv, const float* __restrict__ b,
        __hip_bfloat16* __restrict__ agg1, int n) {
    int tid = threadIdx.x;
    int node_nu = blockIdx.x * 4 + (tid >> 6);
    if (node_nu >= n) return;
    int node = __builtin_amdgcn_readfirstlane(node_nu);
    int lane = tid & 63;
    int half = lane >> 5;          // 0 or 1
    int hl = lane & 31;            // feature-pair index 0..31
    const unsigned* h1u = (const unsigned*)h1s;   // 32 uints per row
    unsigned u_self = h1u[(size_t)node * 32 + hl];
    int beg = rowstart[node], end = rowstart[node + 1];
    float aAl = 0.f, aAh = 0.f, aBl = 0.f, aBh = 0.f;
    int c = beg;
    for (; c + 4 <= end; c += 4) {
        int s0 = csr_src[c + 0], s1 = csr_src[c + 1];   // uniform -> s_load
        int s2 = csr_src[c + 2], s3 = csr_src[c + 3];
        int sA = half ? s1 : s0;
        int sB = half ? s3 : s2;
        unsigned uA = h1u[(size_t)sA * 32 + hl];
        unsigned uB = h1u[(size_t)sB * 32 + hl];
        aAl += bf_lo(uA); aAh += bf_hi(uA);
        aBl += bf_lo(uB); aBh += bf_hi(uB);
    }
    if (c + 2 <= end) {
        int s0 = csr_src[c + 0], s1 = csr_src[c + 1];
        int sA = half ? s1 : s0;
        unsigned uA = h1u[(size_t)sA * 32 + hl];
        aAl += bf_lo(uA); aAh += bf_hi(uA);
        c += 2;
    }
    if (c < end) {
        int s0 = csr_src[c];
        unsigned uA = h1u[(size_t)s0 * 32 + hl];
        if (half == 0) { aAl += bf_lo(uA); aAh += bf_hi(uA); }
    }
    float flo = aAl + aBl;
    float fhi = aAh + aBh;
    flo += __shfl_xor(flo, 32);    // combine the two half-waves
    fhi += __shfl_xor(fhi, 32);
    flo += bf_lo(u_self);
    fhi += bf_hi(u_self);
    float dv = dinv[node];
    float2 bb = *(const float2*)(b + 2 * hl);
    float vlo = fmaxf(flo * dv + bb.x, 0.0f);
    float vhi = fmaxf(fhi * dv + bb.y, 0.0f);
    if (lane < 32)
        ((unsigned*)agg1)[(size_t)node * 32 + hl] = pk_bf16(vlo, vhi);
}

// ================= layer 2 GEMM (MFMA bf16): h2s = bf16( (agg1b @ W2) * dinv ) =================

__global__ __launch_bounds__(256) void gemm2_mfma(const __hip_bfloat16* __restrict__ agg1b,
        const float* __restrict__ W, const float* __restrict__ dinv,
        __hip_bfloat16* __restrict__ h2, int n) {
    __shared__ unsigned As[64 * LDSU];
    int tid = threadIdx.x;
    int lane = tid & 63;
    int w = tid >> 6;
    int q = lane >> 4;
    int c = lane & 15;
    int nodeBase = blockIdx.x * 64;
    const unsigned* a1u = (const unsigned*)agg1b;

    #pragma unroll
    for (int i = 0; i < 8; ++i) {
        int uidx = tid + 256 * i;          // 0..2047
        int row = uidx >> 5, col = uidx & 31;
        int node = nodeBase + row; if (node >= n) node = n - 1;
        As[row * LDSU + col] = a1u[(size_t)node * 32 + col];
    }
    short8 Bf[3][2];
    #pragma unroll
    for (int nt = 0; nt < 3; ++nt) {
        int nn = nt * 16 + c;
        bool valid = (nn < 40);
        #pragma unroll
        for (int kk = 0; kk < 2; ++kk)
            #pragma unroll
            for (int j = 0; j < 8; ++j)
                Bf[nt][kk][j] = valid ? (short)bfbits(W[(kk * 32 + q * 8 + j) * 40 + nn]) : (short)0;
    }
    __syncthreads();

    f32x4 acc[3];
    #pragma unroll
    for (int nt = 0; nt < 3; ++nt) acc[nt] = (f32x4){0.f, 0.f, 0.f, 0.f};
    #pragma unroll
    for (int kk = 0; kk < 2; ++kk) {
        short8 a = *(const short8*)&As[(w * 16 + c) * LDSU + kk * 16 + q * 4];
        #pragma unroll
        for (int nt = 0; nt < 3; ++nt)
            acc[nt] = __builtin_amdgcn_mfma_f32_16x16x32_bf16(a, Bf[nt][kk], acc[nt], 0, 0, 0);
    }
    unsigned short* hu = (unsigned short*)h2;
    #pragma unroll
    for (int r = 0; r < 4; ++r) {
        int node = nodeBase + w * 16 + q * 4 + r;
        if (node < n) {
            float dv = dinv[node];
            #pragma unroll
            for (int nt = 0; nt < 3; ++nt) {
                int nn = nt * 16 + c;
                if (nn < 40)
                    hu[(size_t)node * H2S_STRIDE + nn] = bfbits(acc[nt][r] * dv);
            }
        }
    }
}

// ================= gather layer 2 + fused log_softmax =================

__global__ __launch_bounds__(256) void gather2_kernel(const __hip_bfloat16* __restrict__ h2s,
        const int* __restrict__ rowstart, const int* __restrict__ csr_src,
        const float* __restrict__ dinv, const float* __restrict__ b,
        float* __restrict__ out, int n) {
    int tid = threadIdx.x;
    int node_nu = blockIdx.x * 4 + (tid >> 6);
    if (node_nu >= n) return;
    int node = __builtin_amdgcn_readfirstlane(node_nu);
    int lane = tid & 63;
    int half = lane >> 5;
    int hl = lane & 31;
    int hlc = (hl < 20) ? hl : 19;            // clamp into the valid 40-feature region
    const unsigned* h2u = (const unsigned*)h2s;   // 32 uints per padded row
    unsigned u_self = h2u[(size_t)node * 32 + hlc];
    int beg = rowstart[node], end = rowstart[node + 1];
    float aAl = 0.f, aAh = 0.f, aBl = 0.f, aBh = 0.f;
    int c = beg;
    for (; c + 4 <= end; c += 4) {
        int s0 = csr_src[c + 0], s1 = csr_src[c + 1];
        int s2 = csr_src[c + 2], s3 = csr_src[c + 3];
        int sA = half ? s1 : s0;
        int sB = half ? s3 : s2;
        unsigned uA = h2u[(size_t)sA * 32 + hlc];
        unsigned uB = h2u[(size_t)sB * 32 + hlc];
        aAl += bf_lo(uA); aAh += bf_hi(uA);
        aBl += bf_lo(uB); aBh += bf_hi(uB);
    }
    if (c + 2 <= end) {
        int s0 = csr_src[c + 0], s1 = csr_src[c + 1];
        int sA = half ? s1 : s0;
        unsigned uA = h2u[(size_t)sA * 32 + hlc];
        aAl += bf_lo(uA); aAh += bf_hi(uA);
        c += 2;
    }
    if (c < end) {
        int s0 = csr_src[c];
        unsigned uA = h2u[(size_t)s0 * 32 + hlc];
        if (half == 0) { aAl += bf_lo(uA); aAh += bf_hi(uA); }
    }
    float flo = aAl + aBl;
    float fhi = aAh + aBh;
    flo += __shfl_xor(flo, 32);
    fhi += __shfl_xor(fhi, 32);
    flo += bf_lo(u_self);
    fhi += bf_hi(u_self);
    float dv = dinv[node];
    float2 bb = *(const float2*)(b + 2 * hlc);
    float vlo = flo * dv + bb.x;
    float vhi = fhi * dv + bb.y;
    float mx = (hl < 20) ? fmaxf(vlo, vhi) : -INFINITY;
    #pragma unroll
    for (int off = 16; off; off >>= 1) mx = fmaxf(mx, __shfl_xor(mx, off));
    float e0 = (hl < 20) ? expf(vlo - mx) : 0.0f;
    float e1 = (hl < 20) ? expf(vhi - mx) : 0.0f;
    float sm = e0 + e1;
    #pragma unroll
    for (int off = 16; off; off >>= 1) sm += __shfl_xor(sm, off);
    float ls = mx + logf(sm);
    if (lane < 32 && hl < 20)
        *(float2*)(out + (size_t)node * 40 + 2 * hl) = make_float2(vlo - ls, vhi - ls);
}

extern "C" void kernel_launch(void* const* d_in, const int* in_sizes, int n_in,
                              void* d_out, int out_size, void* d_ws, size_t ws_size,
                              hipStream_t stream) {
    const float* x  = (const float*)d_in[0];
    const int*   ei = (const int*)d_in[1];
    const float* W1 = (const float*)d_in[2];
    const float* b1 = (const float*)d_in[3];
    const float* W2 = (const float*)d_in[4];
    const float* b2 = (const float*)d_in[5];
    float* out = (float*)d_out;

    int N = in_sizes[0] / FIN;     // 100000
    int E = in_sizes[1] / 2;       // 800000
    const int* src = ei;
    const int* dst = ei + E;

    int nbuck = (N + 255) >> 8;              // 391
    int nblkc = (E + CCHUNK - 1) / CCHUNK;   // 196

    char* ws = (char*)d_ws;
    size_t off = 0;
    auto alloc = [&](size_t bytes) {
        void* p = ws + off;
        off = (off + bytes + 255) & ~(size_t)255;
        return p;
    };
    int*             cnt       = (int*)alloc((size_t)nbuck * nblkc * 4);
    int*             total     = (int*)alloc((size_t)nbuck * 4);
    int*             bstart    = (int*)alloc((size_t)(nbuck + 1) * 4);
    unsigned*        ebuf      = (unsigned*)alloc((size_t)E * 4);
    int*             rowstart  = (int*)alloc((size_t)(N + 1) * 4);
    float*           dinv      = (float*)alloc((size_t)N * 4);
    int*             csr_src   = (int*)alloc((size_t)E * 4);
    __hip_bfloat16*  h1s       = (__hip_bfloat16*)alloc((size_t)N * FIN * 2);
    __hip_bfloat16*  agg1b     = (__hip_bfloat16*)alloc((size_t)N * HID * 2);
    __hip_bfloat16*  h2s       = (__hip_bfloat16*)alloc((size_t)N * H2S_STRIDE * 2);

    int gblocks = (N + 63) / 64;   // 1563

    bucket_hist_kernel<<<nblkc, 256, 0, stream>>>(dst, cnt, E, nbuck, nblkc);
    bucket_colscan_kernel<<<nbuck, 256, 0, stream>>>(cnt, total, nblkc);
    bucket_scan_kernel<<<1, 512, 0, stream>>>(total, bstart, nbuck, rowstart, N);
    partition_kernel<<<nblkc, 256, 0, stream>>>(src, dst, cnt, bstart, ebuf, E, nbuck, nblkc);
    build_csr_kernel<<<nbuck, 256, 0, stream>>>(ebuf, bstart, rowstart, dinv, csr_src, N);
    gemm1_mfma<<<gblocks, 256, 0, stream>>>(x, W1, dinv, h1s, N);
    gather1_kernel<<<(N + 3) / 4, 256, 0, stream>>>(h1s, rowstart, csr_src, dinv, b1, agg1b, N);
    gemm2_mfma<<<gblocks, 256, 0, stream>>>(agg1b, W2, dinv, h2s, N);
    gather2_kernel<<<(N + 3) / 4, 256, 0, stream>>>(h2s, rowstart, csr_src, dinv, b2, out, N);
}